// Round 1
// baseline (392.186 us; speedup 1.0000x reference)
//
#include <hip/hip_runtime.h>
#include <hip/hip_bf16.h>
#include <cstdint>

// Problem dims (fixed by reference setup_inputs)
constexpr int Bn = 16;    // batch
constexpr int Sn = 1024;  // source length
constexpr int Tn = 512;   // query steps
constexpr int QD = 256;   // query vec size
constexpr int En = 512;   // src encoding size
constexpr int Hn = 4;     // heads
constexpr float SLOPE = 0.01f;   // jax.nn.leaky_relu default
constexpr float NEG_INF = -1e9f;

// ---------------------------------------------------------------------------
// K0: detect mask dtype (bool bytes vs int32) — writes flag (1 = int32) to ws
// ---------------------------------------------------------------------------
__global__ void detect_mask_kernel(const unsigned char* __restrict__ mask_bytes,
                                   int* __restrict__ flag) {
    __shared__ int cnt;
    if (threadIdx.x == 0) cnt = 0;
    __syncthreads();
    int local = 0;
    for (int p = threadIdx.x; p < Bn * Sn; p += 256) {
        if ((p & 3) != 0 && mask_bytes[p] != 0) local++;
    }
    atomicAdd(&cnt, local);
    __syncthreads();
    if (threadIdx.x == 0) flag[0] = (cnt == 0) ? 1 : 0;
}

// ---------------------------------------------------------------------------
// K1: combined[m,q] = sum_h wc[h] * leaky_relu( (src @ W)[m, h*256+q] )
//     M=16384 (b*s), K=512, output 16384x256
//     Block: 64 rows x 64 q (x 4 heads internally). 256 threads, 4x4x4/thread.
// ---------------------------------------------------------------------------
#define K1_TM 64
#define K1_TQ 64
#define K1_TK 16

__global__ __launch_bounds__(256) void proj_combine_kernel(
    const float* __restrict__ src,    // (16384, 512)
    const float* __restrict__ Wsrc,   // (512, 1024)
    const float* __restrict__ wcomb,  // (4,)
    float* __restrict__ combined)     // (16384, 256)
{
    __shared__ float As[K1_TM][K1_TK + 1];   // padded: avoid 16-way conflicts
    __shared__ float Bs[K1_TK][4 * K1_TQ];   // [k][h*64 + j]

    const int tid = threadIdx.x;
    const int tx = tid & 15, ty = tid >> 4;
    const int m0 = blockIdx.x * K1_TM;
    const int q0 = blockIdx.y * K1_TQ;

    const float wc0 = wcomb[0], wc1 = wcomb[1], wc2 = wcomb[2], wc3 = wcomb[3];

    float acc[4][4][4] = {};  // [h][row i][col j]

    for (int k0 = 0; k0 < En; k0 += K1_TK) {
        // stage A: 64x16, one float4 per thread
        {
            const int r  = tid >> 2;
            const int kk = (tid & 3) * 4;
            const float4 av = *(const float4*)(src + (size_t)(m0 + r) * En + k0 + kk);
            As[r][kk + 0] = av.x; As[r][kk + 1] = av.y;
            As[r][kk + 2] = av.z; As[r][kk + 3] = av.w;
        }
        // stage B: 16 x 256 (4 head-strips of 64 q), 4 float4 per thread
        {
            const int kk = tid >> 4;         // 0..15
            const int c  = (tid & 15) * 16;  // 0..240 (stays within one head strip)
            const int h  = c >> 6;
            const int j  = c & 63;
            const float* g = Wsrc + (size_t)(k0 + kk) * (Hn * QD) + h * QD + q0 + j;
            float4 b0 = ((const float4*)g)[0];
            float4 b1 = ((const float4*)g)[1];
            float4 b2 = ((const float4*)g)[2];
            float4 b3 = ((const float4*)g)[3];
            float4* dst = (float4*)&Bs[kk][c];
            dst[0] = b0; dst[1] = b1; dst[2] = b2; dst[3] = b3;
        }
        __syncthreads();

        #pragma unroll
        for (int k = 0; k < K1_TK; ++k) {
            float a[4];
            #pragma unroll
            for (int i = 0; i < 4; ++i) a[i] = As[ty * 4 + i][k];
            #pragma unroll
            for (int h = 0; h < 4; ++h) {
                const float4 bv = *(const float4*)&Bs[k][h * 64 + tx * 4];
                #pragma unroll
                for (int i = 0; i < 4; ++i) {
                    acc[h][i][0] += a[i] * bv.x;
                    acc[h][i][1] += a[i] * bv.y;
                    acc[h][i][2] += a[i] * bv.z;
                    acc[h][i][3] += a[i] * bv.w;
                }
            }
        }
        __syncthreads();
    }

    // epilogue: leaky_relu + head combine, coalesced float4 store
    #pragma unroll
    for (int i = 0; i < 4; ++i) {
        float vals[4];
        #pragma unroll
        for (int j = 0; j < 4; ++j) {
            float x0 = acc[0][i][j]; x0 = x0 >= 0.f ? x0 : SLOPE * x0;
            float x1 = acc[1][i][j]; x1 = x1 >= 0.f ? x1 : SLOPE * x1;
            float x2 = acc[2][i][j]; x2 = x2 >= 0.f ? x2 : SLOPE * x2;
            float x3 = acc[3][i][j]; x3 = x3 >= 0.f ? x3 : SLOPE * x3;
            vals[j] = wc0 * x0 + wc1 * x1 + wc2 * x2 + wc3 * x3;
        }
        *(float4*)(combined + (size_t)(m0 + ty * 4 + i) * QD + q0 + tx * 4)
            = make_float4(vals[0], vals[1], vals[2], vals[3]);
    }
}

// ---------------------------------------------------------------------------
// K2: weights[t,b,s] = dot(combined[b,s,:], query[t,b,:]) over Q=256,
//     masked rows -> -1e9 * sum(wcomb). Per-b GEMM 1024x512x256.
//     Block: 128 s x 128 t, 256 threads, 8x8 per thread, TK=16.
// ---------------------------------------------------------------------------
#define K2_TS 128
#define K2_TT 128
#define K2_TK 16

__global__ __launch_bounds__(256) void scores_kernel(
    const float* __restrict__ combined,  // (16,1024,256)
    const float* __restrict__ query,     // (512,16,256)
    const void* __restrict__ maskp,      // (16,1024) bool or int32
    const float* __restrict__ wcomb,     // (4,)
    const int* __restrict__ flag,        // 1 = int32 mask
    float* __restrict__ out)             // (512,16,1024) pre-softmax weights
{
    __shared__ float As[K2_TK][K2_TS];  // [k][s]
    __shared__ float Bs[K2_TK][K2_TT];  // [k][t]

    const int tid = threadIdx.x;
    const int tx = tid & 15, ty = tid >> 4;
    const int b  = blockIdx.z;
    const int s0 = blockIdx.x * K2_TS;
    const int t0 = blockIdx.y * K2_TT;

    const float* Amat = combined + (size_t)b * Sn * QD;

    float acc[8][8] = {};  // [s i][t j]

    for (int k0 = 0; k0 < QD; k0 += K2_TK) {
        {
            const int r  = tid >> 1;
            const int kk = (tid & 1) * 8;
            const float* g = Amat + (size_t)(s0 + r) * QD + k0 + kk;
            float4 v0 = ((const float4*)g)[0];
            float4 v1 = ((const float4*)g)[1];
            As[kk + 0][r] = v0.x; As[kk + 1][r] = v0.y;
            As[kk + 2][r] = v0.z; As[kk + 3][r] = v0.w;
            As[kk + 4][r] = v1.x; As[kk + 5][r] = v1.y;
            As[kk + 6][r] = v1.z; As[kk + 7][r] = v1.w;
        }
        {
            const int r  = tid >> 1;
            const int kk = (tid & 1) * 8;
            const float* g = query + (size_t)(t0 + r) * (Bn * QD) + b * QD + k0 + kk;
            float4 v0 = ((const float4*)g)[0];
            float4 v1 = ((const float4*)g)[1];
            Bs[kk + 0][r] = v0.x; Bs[kk + 1][r] = v0.y;
            Bs[kk + 2][r] = v0.z; Bs[kk + 3][r] = v0.w;
            Bs[kk + 4][r] = v1.x; Bs[kk + 5][r] = v1.y;
            Bs[kk + 6][r] = v1.z; Bs[kk + 7][r] = v1.w;
        }
        __syncthreads();

        #pragma unroll
        for (int k = 0; k < K2_TK; ++k) {
            const float4 a0 = *(const float4*)&As[k][ty * 8];
            const float4 a1 = *(const float4*)&As[k][ty * 8 + 4];
            const float4 b0 = *(const float4*)&Bs[k][tx * 8];
            const float4 b1 = *(const float4*)&Bs[k][tx * 8 + 4];
            const float a[8] = {a0.x, a0.y, a0.z, a0.w, a1.x, a1.y, a1.z, a1.w};
            const float bb[8] = {b0.x, b0.y, b0.z, b0.w, b1.x, b1.y, b1.z, b1.w};
            #pragma unroll
            for (int i = 0; i < 8; ++i)
                #pragma unroll
                for (int j = 0; j < 8; ++j)
                    acc[i][j] += a[i] * bb[j];
        }
        __syncthreads();
    }

    // epilogue: mask override + write
    const float sumw = wcomb[0] + wcomb[1] + wcomb[2] + wcomb[3];
    const float maskval = NEG_INF * sumw;
    const bool is_int = (flag[0] != 0);

    bool msk[8];
    #pragma unroll
    for (int i = 0; i < 8; ++i) {
        const int idx = b * Sn + s0 + ty * 8 + i;
        int m;
        if (is_int) m = ((const int*)maskp)[idx];
        else        m = (int)((const unsigned char*)maskp)[idx];
        msk[i] = (m != 0);
    }

    #pragma unroll
    for (int j = 0; j < 8; ++j) {
        const int t = t0 + tx * 8 + j;
        float* orow = out + ((size_t)t * Bn + b) * Sn + s0 + ty * 8;
        float vals[8];
        #pragma unroll
        for (int i = 0; i < 8; ++i) vals[i] = msk[i] ? maskval : acc[i][j];
        *(float4*)(orow + 0) = make_float4(vals[0], vals[1], vals[2], vals[3]);
        *(float4*)(orow + 4) = make_float4(vals[4], vals[5], vals[6], vals[7]);
    }
}

// ---------------------------------------------------------------------------
// K3: in-place softmax over last dim (S=1024). One block per (t,b) row.
// ---------------------------------------------------------------------------
__global__ __launch_bounds__(256) void softmax_kernel(float* __restrict__ out) {
    const size_t row = blockIdx.x;
    float* p = out + row * (size_t)Sn;
    const int tid = threadIdx.x;
    const int lane = tid & 63, wave = tid >> 6;

    float4 v = ((const float4*)p)[tid];

    // row max
    float m = fmaxf(fmaxf(v.x, v.y), fmaxf(v.z, v.w));
    #pragma unroll
    for (int off = 32; off; off >>= 1) m = fmaxf(m, __shfl_down(m, off));
    __shared__ float smax[4];
    __shared__ float sm_all;
    if (lane == 0) smax[wave] = m;
    __syncthreads();
    if (tid == 0) sm_all = fmaxf(fmaxf(smax[0], smax[1]), fmaxf(smax[2], smax[3]));
    __syncthreads();
    m = sm_all;

    // exp + row sum
    float e0 = __expf(v.x - m), e1 = __expf(v.y - m);
    float e2 = __expf(v.z - m), e3 = __expf(v.w - m);
    float s = e0 + e1 + e2 + e3;
    #pragma unroll
    for (int off = 32; off; off >>= 1) s += __shfl_down(s, off);
    __shared__ float ssum[4];
    __shared__ float ss_all;
    if (lane == 0) ssum[wave] = s;
    __syncthreads();
    if (tid == 0) ss_all = ssum[0] + ssum[1] + ssum[2] + ssum[3];
    __syncthreads();
    const float inv = 1.0f / ss_all;

    ((float4*)p)[tid] = make_float4(e0 * inv, e1 * inv, e2 * inv, e3 * inv);
}

// ---------------------------------------------------------------------------
extern "C" void kernel_launch(void* const* d_in, const int* in_sizes, int n_in,
                              void* d_out, int out_size, void* d_ws, size_t ws_size,
                              hipStream_t stream) {
    const float* src   = (const float*)d_in[0];  // (16,1024,512)
    const void*  maskp = d_in[1];                // (16,1024) bool/int32
    const float* query = (const float*)d_in[2];  // (512,16,256)
    const float* Wsrc  = (const float*)d_in[3];  // (512,1024)
    const float* wcomb = (const float*)d_in[4];  // (4,)
    float* out = (float*)d_out;                  // (512,16,1024)

    int*   flag     = (int*)d_ws;
    float* combined = (float*)((char*)d_ws + 256);  // 16384*256 fp32 = 16 MB

    detect_mask_kernel<<<1, 256, 0, stream>>>((const unsigned char*)maskp, flag);

    {
        dim3 grid(Bn * Sn / K1_TM, QD / K1_TQ);  // (256, 4)
        proj_combine_kernel<<<grid, 256, 0, stream>>>(src, Wsrc, wcomb, combined);
    }
    {
        dim3 grid(Sn / K2_TS, Tn / K2_TT, Bn);   // (8, 4, 16)
        scores_kernel<<<grid, 256, 0, stream>>>(combined, query, maskp, wcomb, flag, out);
    }
    {
        softmax_kernel<<<Tn * Bn, 256, 0, stream>>>(out);
    }
}

// Round 2
// 225.521 us; speedup vs baseline: 1.7390x; 1.7390x over previous
//
#include <hip/hip_runtime.h>
#include <hip/hip_bf16.h>
#include <cstdint>

// Problem dims (fixed by reference setup_inputs)
constexpr int Bn = 16;    // batch
constexpr int Sn = 1024;  // source length
constexpr int Tn = 512;   // query steps
constexpr int QD = 256;   // query vec size
constexpr int En = 512;   // src encoding size
constexpr int Hn = 4;     // heads
constexpr float SLOPE = 0.01f;   // jax.nn.leaky_relu default
constexpr float NEG_INF = -1e9f;
constexpr int Mn = Bn * Sn;      // 16384 rows of the projection GEMM

typedef _Float16 f16;
typedef f16 f16x4 __attribute__((ext_vector_type(4)));
typedef f16 f16x8 __attribute__((ext_vector_type(8)));
typedef float f32x4 __attribute__((ext_vector_type(4)));

// async global->LDS, 16B per lane; dest = wave-uniform base + lane*16
#define G2L(g, l) __builtin_amdgcn_global_load_lds(                      \
    (const __attribute__((address_space(1))) void*)(g),                  \
    (__attribute__((address_space(3))) void*)(l), 16, 0, 0)

// ---------------------------------------------------------------------------
// K0: detect mask dtype (bool bytes vs int32) — writes flag (1 = int32) to ws
// ---------------------------------------------------------------------------
__global__ void detect_mask_kernel(const unsigned char* __restrict__ mask_bytes,
                                   int* __restrict__ flag) {
    __shared__ int cnt;
    if (threadIdx.x == 0) cnt = 0;
    __syncthreads();
    int local = 0;
    for (int p = threadIdx.x; p < Bn * Sn; p += 256) {
        if ((p & 3) != 0 && mask_bytes[p] != 0) local++;
    }
    atomicAdd(&cnt, local);
    __syncthreads();
    if (threadIdx.x == 0) flag[0] = (cnt == 0) ? 1 : 0;
}

// ---------------------------------------------------------------------------
// C1: split src (16384x512 f32) into Ah + Al (f16 row-major), exact hi/lo
// ---------------------------------------------------------------------------
__global__ __launch_bounds__(256) void conv_a_kernel(
    const float* __restrict__ src, f16* __restrict__ Ah, f16* __restrict__ Al)
{
    const size_t i4 = (size_t)blockIdx.x * 256 + threadIdx.x;  // float4 index
    const size_t base = i4 * 4;
    const float4 v = *(const float4*)(src + base);
    f16x4 hi, lo;
    const float xs[4] = {v.x, v.y, v.z, v.w};
    #pragma unroll
    for (int j = 0; j < 4; ++j) {
        f16 h = (f16)xs[j];
        hi[j] = h;
        lo[j] = (f16)(xs[j] - (float)h);
    }
    *(f16x4*)(Ah + base) = hi;
    *(f16x4*)(Al + base) = lo;
}

// ---------------------------------------------------------------------------
// C2: W (512x1024 f32) -> Bht, Blt (1024x512 f16) transposed + hi/lo split
// ---------------------------------------------------------------------------
__global__ __launch_bounds__(256) void conv_b_kernel(
    const float* __restrict__ W, f16* __restrict__ Bht, f16* __restrict__ Blt)
{
    __shared__ float T[64][65];
    const int tid = threadIdx.x;
    const int n0 = blockIdx.x * 64;   // 16 tiles
    const int k0 = blockIdx.y * 64;   // 8 tiles
    #pragma unroll
    for (int p = 0; p < 4; ++p) {
        const int e = p * 256 + tid;
        const int r = e >> 4;        // k-dir row 0..63
        const int c4 = e & 15;       // n-dir float4 group
        const float4 v = *(const float4*)(W + (size_t)(k0 + r) * (Hn * QD) + n0 + c4 * 4);
        T[r][c4 * 4 + 0] = v.x; T[r][c4 * 4 + 1] = v.y;
        T[r][c4 * 4 + 2] = v.z; T[r][c4 * 4 + 3] = v.w;
    }
    __syncthreads();
    #pragma unroll
    for (int p = 0; p < 4; ++p) {
        const int e = p * 256 + tid;
        const int r = e >> 4;        // n-dir row 0..63
        const int c4 = e & 15;       // k-dir group
        f16x4 hi, lo;
        #pragma unroll
        for (int j = 0; j < 4; ++j) {
            const float x = T[c4 * 4 + j][r];
            f16 h = (f16)x;
            hi[j] = h;
            lo[j] = (f16)(x - (float)h);
        }
        const size_t off = (size_t)(n0 + r) * En + k0 + c4 * 4;
        *(f16x4*)(Bht + off) = hi;
        *(f16x4*)(Blt + off) = lo;
    }
}

// ---------------------------------------------------------------------------
// K1: combined = head-combine(leaky_relu(src @ W)) via f16-split MFMA.
//   3 K-phases: Ah*Bh + Al*Bh + Ah*Bl  (K=512 each, BK=32, 16x16x32_f16)
//   Block tile: 128 rows x 128 cols where cols = [qblk(2)][head(4)][qin(16)]
//   4 waves 2x2, each 64x64. Epilogue combines heads thread-locally.
//   LDS layout [koff(4)][row/col(128)][kk(8)] f16: staging writes and
//   ds_read_b128 fragment reads are both contiguous 16B chunks.
// ---------------------------------------------------------------------------
__global__ __launch_bounds__(256) void gemm_f16split_kernel(
    const f16* __restrict__ Ah, const f16* __restrict__ Al,
    const f16* __restrict__ Bht, const f16* __restrict__ Blt,
    const float* __restrict__ wcomb,
    float* __restrict__ combined)
{
    __shared__ f16 As[4096];   // 8 KB
    __shared__ f16 Bs[4096];   // 8 KB

    const int tid = threadIdx.x;
    const int l  = tid & 63;
    const int wv = tid >> 6;
    const int wr = wv >> 1, wcx = wv & 1;
    const int m0 = blockIdx.x * 128;
    const int q0 = blockIdx.y * 32;

    // staging source indices (per thread handles chunk tid and tid+256)
    const int rA = tid & 127;            // A row within tile
    const int kA = (tid >> 7) * 8;       // koff*8: 0 or 8 (call1 adds 16)
    const int colB = tid & 127;
    const int nB = ((colB >> 4) & 3) * QD + q0 + (colB >> 6) * 16 + (colB & 15);
    const int kB = (tid >> 7) * 8;

    // fragment ds_read bases (halves); each 16-lane group reads 256B contiguous
    const int baseA = ((l >> 4) * 128 + wr * 64 + (l & 15)) * 8;
    const int baseB = ((l >> 4) * 128 + wcx * 64 + (l & 15)) * 8;

    f32x4 acc[4][4];
    const f32x4 zz = {0.f, 0.f, 0.f, 0.f};
    #pragma unroll
    for (int m = 0; m < 4; ++m)
        #pragma unroll
        for (int h = 0; h < 4; ++h) acc[m][h] = zz;

    for (int kk = 0; kk < 48; ++kk) {
        const int ph = kk >> 4;
        const int k0 = (kk & 15) * 32;
        const f16* Ap = (ph == 1) ? Al : Ah;
        const f16* Bp = (ph == 2) ? Blt : Bht;
        const f16* ga = Ap + (size_t)(m0 + rA) * En + kA + k0;
        const f16* gb = Bp + (size_t)nB * En + kB + k0;
        G2L(ga,      As + wv * 512);
        G2L(ga + 16, As + 2048 + wv * 512);
        G2L(gb,      Bs + wv * 512);
        G2L(gb + 16, Bs + 2048 + wv * 512);
        __syncthreads();   // compiler drains vmcnt before s_barrier

        f16x8 af[4], bf[4];
        #pragma unroll
        for (int m = 0; m < 4; ++m) af[m] = *(const f16x8*)(As + baseA + m * 128);
        #pragma unroll
        for (int h = 0; h < 4; ++h) bf[h] = *(const f16x8*)(Bs + baseB + h * 128);

        #pragma unroll
        for (int m = 0; m < 4; ++m)
            #pragma unroll
            for (int h = 0; h < 4; ++h)
                acc[m][h] = __builtin_amdgcn_mfma_f32_16x16x32_f16(
                    af[m], bf[h], acc[m][h], 0, 0, 0);
        __syncthreads();
    }

    // epilogue: leaky_relu + head combine (all 4 heads live in this thread)
    const float w0 = wcomb[0], w1 = wcomb[1], w2 = wcomb[2], w3 = wcomb[3];
    const int row_base = m0 + wr * 64 + (l >> 4) * 4;  // + m*16 + i
    const int q = q0 + wcx * 16 + (l & 15);
    #pragma unroll
    for (int m = 0; m < 4; ++m) {
        #pragma unroll
        for (int i = 0; i < 4; ++i) {
            float x0 = acc[m][0][i]; x0 = x0 >= 0.f ? x0 : SLOPE * x0;
            float x1 = acc[m][1][i]; x1 = x1 >= 0.f ? x1 : SLOPE * x1;
            float x2 = acc[m][2][i]; x2 = x2 >= 0.f ? x2 : SLOPE * x2;
            float x3 = acc[m][3][i]; x3 = x3 >= 0.f ? x3 : SLOPE * x3;
            combined[(size_t)(row_base + m * 16 + i) * QD + q]
                = w0 * x0 + w1 * x1 + w2 * x2 + w3 * x3;
        }
    }
}

// ---------------------------------------------------------------------------
// K2: weights[t,b,s] = dot(combined[b,s,:], query[t,b,:]) over Q=256,
//     masked rows -> -1e9 * sum(wcomb). Per-b GEMM 1024x512x256 (fp32 VALU).
// ---------------------------------------------------------------------------
#define K2_TS 128
#define K2_TT 128
#define K2_TK 16

__global__ __launch_bounds__(256) void scores_kernel(
    const float* __restrict__ combined,  // (16,1024,256)
    const float* __restrict__ query,     // (512,16,256)
    const void* __restrict__ maskp,      // (16,1024) bool or int32
    const float* __restrict__ wcomb,     // (4,)
    const int* __restrict__ flag,        // 1 = int32 mask
    float* __restrict__ out)             // (512,16,1024) pre-softmax weights
{
    __shared__ float As2[K2_TK][K2_TS];
    __shared__ float Bs2[K2_TK][K2_TT];

    const int tid = threadIdx.x;
    const int tx = tid & 15, ty = tid >> 4;
    const int b  = blockIdx.z;
    const int s0 = blockIdx.x * K2_TS;
    const int t0 = blockIdx.y * K2_TT;

    const float* Amat = combined + (size_t)b * Sn * QD;

    float acc[8][8] = {};

    for (int k0 = 0; k0 < QD; k0 += K2_TK) {
        {
            const int r  = tid >> 1;
            const int kk = (tid & 1) * 8;
            const float* g = Amat + (size_t)(s0 + r) * QD + k0 + kk;
            float4 v0 = ((const float4*)g)[0];
            float4 v1 = ((const float4*)g)[1];
            As2[kk + 0][r] = v0.x; As2[kk + 1][r] = v0.y;
            As2[kk + 2][r] = v0.z; As2[kk + 3][r] = v0.w;
            As2[kk + 4][r] = v1.x; As2[kk + 5][r] = v1.y;
            As2[kk + 6][r] = v1.z; As2[kk + 7][r] = v1.w;
        }
        {
            const int r  = tid >> 1;
            const int kk = (tid & 1) * 8;
            const float* g = query + (size_t)(t0 + r) * (Bn * QD) + b * QD + k0 + kk;
            float4 v0 = ((const float4*)g)[0];
            float4 v1 = ((const float4*)g)[1];
            Bs2[kk + 0][r] = v0.x; Bs2[kk + 1][r] = v0.y;
            Bs2[kk + 2][r] = v0.z; Bs2[kk + 3][r] = v0.w;
            Bs2[kk + 4][r] = v1.x; Bs2[kk + 5][r] = v1.y;
            Bs2[kk + 6][r] = v1.z; Bs2[kk + 7][r] = v1.w;
        }
        __syncthreads();

        #pragma unroll
        for (int k = 0; k < K2_TK; ++k) {
            const float4 a0 = *(const float4*)&As2[k][ty * 8];
            const float4 a1 = *(const float4*)&As2[k][ty * 8 + 4];
            const float4 b0 = *(const float4*)&Bs2[k][tx * 8];
            const float4 b1 = *(const float4*)&Bs2[k][tx * 8 + 4];
            const float a[8] = {a0.x, a0.y, a0.z, a0.w, a1.x, a1.y, a1.z, a1.w};
            const float bb[8] = {b0.x, b0.y, b0.z, b0.w, b1.x, b1.y, b1.z, b1.w};
            #pragma unroll
            for (int i = 0; i < 8; ++i)
                #pragma unroll
                for (int j = 0; j < 8; ++j)
                    acc[i][j] += a[i] * bb[j];
        }
        __syncthreads();
    }

    const float sumw = wcomb[0] + wcomb[1] + wcomb[2] + wcomb[3];
    const float maskval = NEG_INF * sumw;
    const bool is_int = (flag[0] != 0);

    bool msk[8];
    #pragma unroll
    for (int i = 0; i < 8; ++i) {
        const int idx = b * Sn + s0 + ty * 8 + i;
        int m;
        if (is_int) m = ((const int*)maskp)[idx];
        else        m = (int)((const unsigned char*)maskp)[idx];
        msk[i] = (m != 0);
    }

    #pragma unroll
    for (int j = 0; j < 8; ++j) {
        const int t = t0 + tx * 8 + j;
        float* orow = out + ((size_t)t * Bn + b) * Sn + s0 + ty * 8;
        float vals[8];
        #pragma unroll
        for (int i = 0; i < 8; ++i) vals[i] = msk[i] ? maskval : acc[i][j];
        *(float4*)(orow + 0) = make_float4(vals[0], vals[1], vals[2], vals[3]);
        *(float4*)(orow + 4) = make_float4(vals[4], vals[5], vals[6], vals[7]);
    }
}

// ---------------------------------------------------------------------------
// K3: in-place softmax over last dim (S=1024). One block per (t,b) row.
// ---------------------------------------------------------------------------
__global__ __launch_bounds__(256) void softmax_kernel(float* __restrict__ out) {
    const size_t row = blockIdx.x;
    float* p = out + row * (size_t)Sn;
    const int tid = threadIdx.x;
    const int lane = tid & 63, wave = tid >> 6;

    float4 v = ((const float4*)p)[tid];

    float m = fmaxf(fmaxf(v.x, v.y), fmaxf(v.z, v.w));
    #pragma unroll
    for (int off = 32; off; off >>= 1) m = fmaxf(m, __shfl_down(m, off));
    __shared__ float smax[4];
    __shared__ float sm_all;
    if (lane == 0) smax[wave] = m;
    __syncthreads();
    if (tid == 0) sm_all = fmaxf(fmaxf(smax[0], smax[1]), fmaxf(smax[2], smax[3]));
    __syncthreads();
    m = sm_all;

    float e0 = __expf(v.x - m), e1 = __expf(v.y - m);
    float e2 = __expf(v.z - m), e3 = __expf(v.w - m);
    float s = e0 + e1 + e2 + e3;
    #pragma unroll
    for (int off = 32; off; off >>= 1) s += __shfl_down(s, off);
    __shared__ float ssum[4];
    __shared__ float ss_all;
    if (lane == 0) ssum[wave] = s;
    __syncthreads();
    if (tid == 0) ss_all = ssum[0] + ssum[1] + ssum[2] + ssum[3];
    __syncthreads();
    const float inv = 1.0f / ss_all;

    ((float4*)p)[tid] = make_float4(e0 * inv, e1 * inv, e2 * inv, e3 * inv);
}

// ---------------------------------------------------------------------------
extern "C" void kernel_launch(void* const* d_in, const int* in_sizes, int n_in,
                              void* d_out, int out_size, void* d_ws, size_t ws_size,
                              hipStream_t stream) {
    const float* src   = (const float*)d_in[0];  // (16,1024,512)
    const void*  maskp = d_in[1];                // (16,1024) bool/int32
    const float* query = (const float*)d_in[2];  // (512,16,256)
    const float* Wsrc  = (const float*)d_in[3];  // (512,1024)
    const float* wcomb = (const float*)d_in[4];  // (4,)
    float* out = (float*)d_out;                  // (512,16,1024)

    // workspace layout (bytes)
    char* ws = (char*)d_ws;
    int*  flag     = (int*)ws;                                  // 4 B
    f16*  Ah       = (f16*)(ws + 256);                          // 16 MB
    f16*  Al       = (f16*)(ws + 256 + (size_t)16 * 1024 * 1024);
    f16*  Bht      = (f16*)(ws + 256 + (size_t)32 * 1024 * 1024);  // 1 MB
    f16*  Blt      = (f16*)(ws + 256 + (size_t)33 * 1024 * 1024);  // 1 MB
    float* combined = (float*)(ws + 256 + (size_t)34 * 1024 * 1024); // 16 MB

    detect_mask_kernel<<<1, 256, 0, stream>>>((const unsigned char*)maskp, flag);

    conv_a_kernel<<<(Mn * En) / (256 * 4), 256, 0, stream>>>(src, Ah, Al);
    {
        dim3 grid((Hn * QD) / 64, En / 64);  // (16, 8)
        conv_b_kernel<<<grid, 256, 0, stream>>>(Wsrc, Bht, Blt);
    }
    {
        dim3 grid(Mn / 128, QD / 32);        // (128, 8)
        gemm_f16split_kernel<<<grid, 256, 0, stream>>>(Ah, Al, Bht, Blt, wcomb, combined);
    }
    {
        dim3 grid(Sn / K2_TS, Tn / K2_TT, Bn);  // (8, 4, 16)
        scores_kernel<<<grid, 256, 0, stream>>>(combined, query, maskp, wcomb, flag, out);
    }
    softmax_kernel<<<Tn * Bn, 256, 0, stream>>>(out);
}

// Round 3
// 177.182 us; speedup vs baseline: 2.2135x; 1.2728x over previous
//
#include <hip/hip_runtime.h>
#include <hip/hip_bf16.h>
#include <cstdint>

// Problem dims (fixed by reference setup_inputs)
constexpr int Bn = 16;    // batch
constexpr int Sn = 1024;  // source length
constexpr int Tn = 512;   // query steps
constexpr int QD = 256;   // query vec size
constexpr int En = 512;   // src encoding size
constexpr int Hn = 4;     // heads
constexpr float SLOPE = 0.01f;   // jax.nn.leaky_relu default
constexpr float NEG_INF = -1e9f;
constexpr int Mn = Bn * Sn;      // 16384 rows of the projection GEMM

typedef _Float16 f16;
typedef f16 f16x4 __attribute__((ext_vector_type(4)));
typedef f16 f16x8 __attribute__((ext_vector_type(8)));
typedef float f32x4 __attribute__((ext_vector_type(4)));

// async global->LDS, 16B per lane; dest = wave-uniform base + lane*16
#define G2L(g, l) __builtin_amdgcn_global_load_lds(                      \
    (const __attribute__((address_space(1))) void*)(g),                  \
    (__attribute__((address_space(3))) void*)(l), 16, 0, 0)

// ---------------------------------------------------------------------------
// K0: detect mask dtype (bool bytes vs int32) — writes flag (1 = int32) to ws
// ---------------------------------------------------------------------------
__global__ void detect_mask_kernel(const unsigned char* __restrict__ mask_bytes,
                                   int* __restrict__ flag) {
    __shared__ int cnt;
    if (threadIdx.x == 0) cnt = 0;
    __syncthreads();
    int local = 0;
    for (int p = threadIdx.x; p < 4096; p += 256) {
        if ((p & 3) != 0 && mask_bytes[p] != 0) local++;
    }
    atomicAdd(&cnt, local);
    __syncthreads();
    if (threadIdx.x == 0) flag[0] = (cnt == 0) ? 1 : 0;
}

// ---------------------------------------------------------------------------
// C1: split src (16384x512 f32) into Ah + Al (f16 row-major), exact hi/lo
// ---------------------------------------------------------------------------
__global__ __launch_bounds__(256) void conv_a_kernel(
    const float* __restrict__ src, f16* __restrict__ Ah, f16* __restrict__ Al)
{
    const size_t i4 = (size_t)blockIdx.x * 256 + threadIdx.x;
    const size_t base = i4 * 4;
    const float4 v = *(const float4*)(src + base);
    f16x4 hi, lo;
    const float xs[4] = {v.x, v.y, v.z, v.w};
    #pragma unroll
    for (int j = 0; j < 4; ++j) {
        f16 h = (f16)xs[j];
        hi[j] = h;
        lo[j] = (f16)(xs[j] - (float)h);
    }
    *(f16x4*)(Ah + base) = hi;
    *(f16x4*)(Al + base) = lo;
}

// ---------------------------------------------------------------------------
// C2: W (512x1024 f32) -> Bht, Blt (1024x512 f16) transposed + hi/lo split
// ---------------------------------------------------------------------------
__global__ __launch_bounds__(256) void conv_b_kernel(
    const float* __restrict__ W, f16* __restrict__ Bht, f16* __restrict__ Blt)
{
    __shared__ float T[64][65];
    const int tid = threadIdx.x;
    const int n0 = blockIdx.x * 64;
    const int k0 = blockIdx.y * 64;
    #pragma unroll
    for (int p = 0; p < 4; ++p) {
        const int e = p * 256 + tid;
        const int r = e >> 4;
        const int c4 = e & 15;
        const float4 v = *(const float4*)(W + (size_t)(k0 + r) * (Hn * QD) + n0 + c4 * 4);
        T[r][c4 * 4 + 0] = v.x; T[r][c4 * 4 + 1] = v.y;
        T[r][c4 * 4 + 2] = v.z; T[r][c4 * 4 + 3] = v.w;
    }
    __syncthreads();
    #pragma unroll
    for (int p = 0; p < 4; ++p) {
        const int e = p * 256 + tid;
        const int r = e >> 4;
        const int c4 = e & 15;
        f16x4 hi, lo;
        #pragma unroll
        for (int j = 0; j < 4; ++j) {
            const float x = T[c4 * 4 + j][r];
            f16 h = (f16)x;
            hi[j] = h;
            lo[j] = (f16)(x - (float)h);
        }
        const size_t off = (size_t)(n0 + r) * En + k0 + c4 * 4;
        *(f16x4*)(Bht + off) = hi;
        *(f16x4*)(Blt + off) = lo;
    }
}

// ---------------------------------------------------------------------------
// C3: split query (512,16,256) f32 -> Qh, Ql (b,t,q) f16. Runs AFTER gemm1
//     (its outputs alias the Ah/Al workspace region).
// ---------------------------------------------------------------------------
__global__ __launch_bounds__(256) void conv_q_kernel(
    const float* __restrict__ query, f16* __restrict__ Qh, f16* __restrict__ Ql)
{
    const int tid = threadIdx.x;
    const int rloc = tid >> 6;
    const int lane = tid & 63;
    const int row = blockIdx.x * 4 + rloc;   // (t,b) pair, t-major
    const int t = row >> 4, b = row & 15;
    const float4 v = *(const float4*)(query + (size_t)row * QD + lane * 4);
    f16x4 hi, lo;
    const float xs[4] = {v.x, v.y, v.z, v.w};
    #pragma unroll
    for (int j = 0; j < 4; ++j) {
        f16 h = (f16)xs[j];
        hi[j] = h;
        lo[j] = (f16)(xs[j] - (float)h);
    }
    const size_t off = ((size_t)(b * Tn + t)) * QD + lane * 4;
    *(f16x4*)(Qh + off) = hi;
    *(f16x4*)(Ql + off) = lo;
}

// ---------------------------------------------------------------------------
// K1: Ch/Cl = f16-split of head-combine(leaky_relu(src @ W)) via MFMA.
//   3 K-phases: Ah*Bh, Al*Bh, Ah*Bl (K=512 each, BK=32, 16x16x32_f16).
//   128x128 block tile (cols = [qblk2][head4][q16]); 4 waves 2x2.
//   2-phase double-buffered: stage tile t+1 while computing tile t.
// ---------------------------------------------------------------------------
__global__ __launch_bounds__(256) void gemm1_kernel(
    const f16* __restrict__ Ah, const f16* __restrict__ Al,
    const f16* __restrict__ Bht, const f16* __restrict__ Blt,
    const float* __restrict__ wcomb,
    f16* __restrict__ Ch, f16* __restrict__ Cl)
{
    __shared__ f16 A0[4096], A1[4096], B0[4096], B1[4096];

    const int tid = threadIdx.x;
    const int l  = tid & 63;
    const int wv = tid >> 6;
    const int wr = wv >> 1, wcx = wv & 1;
    const int m0 = blockIdx.x * 128;
    const int q0 = blockIdx.y * 32;

    const f16* Aps[3] = {Ah, Al, Ah};
    const f16* Bps[3] = {Bht, Bht, Blt};

    const int rA = tid & 127;
    const int kA = (tid >> 7) * 8;
    const int colB = tid & 127;
    const int nB = ((colB >> 4) & 3) * QD + q0 + (colB >> 6) * 16 + (colB & 15);

    const int baseA = ((l >> 4) * 128 + wr * 64 + (l & 15)) * 8;
    const int baseB = ((l >> 4) * 128 + wcx * 64 + (l & 15)) * 8;

    f32x4 acc[4][4];
    const f32x4 zz = {0.f, 0.f, 0.f, 0.f};
    #pragma unroll
    for (int m = 0; m < 4; ++m)
        #pragma unroll
        for (int h = 0; h < 4; ++h) acc[m][h] = zz;

    auto stage = [&](int t, f16* As, f16* Bs) {
        const int ph = t >> 4;
        const int k0 = (t & 15) * 32;
        const f16* ga = Aps[ph] + (size_t)(m0 + rA) * En + kA + k0;
        const f16* gb = Bps[ph] + (size_t)nB * En + kA + k0;
        G2L(ga,      As + wv * 512);
        G2L(ga + 16, As + 2048 + wv * 512);
        G2L(gb,      Bs + wv * 512);
        G2L(gb + 16, Bs + 2048 + wv * 512);
    };
    auto compute = [&](const f16* As, const f16* Bs) {
        f16x8 af[4], bf[4];
        #pragma unroll
        for (int m = 0; m < 4; ++m) af[m] = *(const f16x8*)(As + baseA + m * 128);
        #pragma unroll
        for (int h = 0; h < 4; ++h) bf[h] = *(const f16x8*)(Bs + baseB + h * 128);
        #pragma unroll
        for (int m = 0; m < 4; ++m)
            #pragma unroll
            for (int h = 0; h < 4; ++h)
                acc[m][h] = __builtin_amdgcn_mfma_f32_16x16x32_f16(
                    af[m], bf[h], acc[m][h], 0, 0, 0);
    };

    stage(0, A0, B0);
    __syncthreads();
    for (int t = 0; t < 48; t += 2) {
        stage(t + 1, A1, B1);       // prefetch overlaps with compute(A0)
        compute(A0, B0);
        __syncthreads();            // drains vmcnt -> buf1 ready, buf0 free
        if (t + 2 < 48) stage(t + 2, A0, B0);
        compute(A1, B1);
        __syncthreads();
    }

    // epilogue: leaky_relu + head combine + hi/lo split store
    const float w0 = wcomb[0], w1 = wcomb[1], w2 = wcomb[2], w3 = wcomb[3];
    const int row_base = m0 + wr * 64 + (l >> 4) * 4;
    const int q = q0 + wcx * 16 + (l & 15);
    #pragma unroll
    for (int m = 0; m < 4; ++m) {
        #pragma unroll
        for (int i = 0; i < 4; ++i) {
            float x0 = acc[m][0][i]; x0 = x0 >= 0.f ? x0 : SLOPE * x0;
            float x1 = acc[m][1][i]; x1 = x1 >= 0.f ? x1 : SLOPE * x1;
            float x2 = acc[m][2][i]; x2 = x2 >= 0.f ? x2 : SLOPE * x2;
            float x3 = acc[m][3][i]; x3 = x3 >= 0.f ? x3 : SLOPE * x3;
            const float c = w0 * x0 + w1 * x1 + w2 * x2 + w3 * x3;
            const f16 ch = (f16)c;
            const f16 cl = (f16)(c - (float)ch);
            const size_t off = (size_t)(row_base + m * 16 + i) * QD + q;
            Ch[off] = ch;
            Cl[off] = cl;
        }
    }
}

// ---------------------------------------------------------------------------
// K2: out[t,b,s] = dot(combined[b,s,:], query[t,b,:]) via f16-split MFMA.
//   Per batch: M=1024(s) N=512(t) K=256. Phases Ch*Qh, Cl*Qh, Ch*Ql.
//   128x128 tile, BK=32, 24 steps, 2-phase double-buffered.
//   Epilogue: mask override, store to (T,B,S).
// ---------------------------------------------------------------------------
__global__ __launch_bounds__(256) void gemm2_kernel(
    const f16* __restrict__ Ch, const f16* __restrict__ Cl,
    const f16* __restrict__ Qh, const f16* __restrict__ Ql,
    const void* __restrict__ maskp, const float* __restrict__ wcomb,
    const int* __restrict__ flag,
    float* __restrict__ out)
{
    __shared__ f16 A0[4096], A1[4096], B0[4096], B1[4096];

    const int tid = threadIdx.x;
    const int l  = tid & 63;
    const int wv = tid >> 6;
    const int wr = wv >> 1, wcx = wv & 1;
    const int b  = blockIdx.z;
    const int s0 = blockIdx.x * 128;
    const int t0 = blockIdx.y * 128;

    const f16* Aps[3] = {Ch, Cl, Ch};
    const f16* Bps[3] = {Qh, Qh, Ql};

    const int rA = tid & 127;
    const int kA = (tid >> 7) * 8;
    const int colB = tid & 127;

    const int baseA = ((l >> 4) * 128 + wr * 64 + (l & 15)) * 8;
    const int baseB = ((l >> 4) * 128 + wcx * 64 + (l & 15)) * 8;

    f32x4 acc[4][4];
    const f32x4 zz = {0.f, 0.f, 0.f, 0.f};
    #pragma unroll
    for (int m = 0; m < 4; ++m)
        #pragma unroll
        for (int n = 0; n < 4; ++n) acc[m][n] = zz;

    auto stage = [&](int t, f16* As, f16* Bs) {
        const int ph = t >> 3;
        const int k0 = (t & 7) * 32;
        const f16* ga = Aps[ph] + ((size_t)(b * Sn + s0 + rA)) * QD + kA + k0;
        const f16* gb = Bps[ph] + ((size_t)(b * Tn + t0 + colB)) * QD + kA + k0;
        G2L(ga,      As + wv * 512);
        G2L(ga + 16, As + 2048 + wv * 512);
        G2L(gb,      Bs + wv * 512);
        G2L(gb + 16, Bs + 2048 + wv * 512);
    };
    auto compute = [&](const f16* As, const f16* Bs) {
        f16x8 af[4], bf[4];
        #pragma unroll
        for (int m = 0; m < 4; ++m) af[m] = *(const f16x8*)(As + baseA + m * 128);
        #pragma unroll
        for (int n = 0; n < 4; ++n) bf[n] = *(const f16x8*)(Bs + baseB + n * 128);
        #pragma unroll
        for (int m = 0; m < 4; ++m)
            #pragma unroll
            for (int n = 0; n < 4; ++n)
                acc[m][n] = __builtin_amdgcn_mfma_f32_16x16x32_f16(
                    af[m], bf[n], acc[m][n], 0, 0, 0);
    };

    stage(0, A0, B0);
    __syncthreads();
    for (int t = 0; t < 24; t += 2) {
        stage(t + 1, A1, B1);
        compute(A0, B0);
        __syncthreads();
        if (t + 2 < 24) stage(t + 2, A0, B0);
        compute(A1, B1);
        __syncthreads();
    }

    // epilogue: mask override + coalesced float4 stores along s
    const float sumw = wcomb[0] + wcomb[1] + wcomb[2] + wcomb[3];
    const float maskval = NEG_INF * sumw;
    const bool is_int = (flag[0] != 0);
    const int rbase = s0 + wr * 64 + (l >> 4) * 4;  // + m*16 + i

    bool msk[4][4];
    #pragma unroll
    for (int m = 0; m < 4; ++m)
        #pragma unroll
        for (int i = 0; i < 4; ++i) {
            const int idx = b * Sn + rbase + m * 16 + i;
            int mm;
            if (is_int) mm = ((const int*)maskp)[idx];
            else        mm = (int)((const unsigned char*)maskp)[idx];
            msk[m][i] = (mm != 0);
        }

    #pragma unroll
    for (int m = 0; m < 4; ++m)
        #pragma unroll
        for (int n = 0; n < 4; ++n) {
            const int t = t0 + wcx * 64 + n * 16 + (l & 15);
            float vals[4];
            #pragma unroll
            for (int i = 0; i < 4; ++i)
                vals[i] = msk[m][i] ? maskval : acc[m][n][i];
            *(float4*)(out + ((size_t)t * Bn + b) * Sn + rbase + m * 16)
                = make_float4(vals[0], vals[1], vals[2], vals[3]);
        }
}

// ---------------------------------------------------------------------------
// K3: in-place softmax over last dim (S=1024). One block per (t,b) row.
// ---------------------------------------------------------------------------
__global__ __launch_bounds__(256) void softmax_kernel(float* __restrict__ out) {
    const size_t row = blockIdx.x;
    float* p = out + row * (size_t)Sn;
    const int tid = threadIdx.x;
    const int lane = tid & 63, wave = tid >> 6;

    float4 v = ((const float4*)p)[tid];

    float m = fmaxf(fmaxf(v.x, v.y), fmaxf(v.z, v.w));
    #pragma unroll
    for (int off = 32; off; off >>= 1) m = fmaxf(m, __shfl_down(m, off));
    __shared__ float smax[4];
    __shared__ float sm_all;
    if (lane == 0) smax[wave] = m;
    __syncthreads();
    if (tid == 0) sm_all = fmaxf(fmaxf(smax[0], smax[1]), fmaxf(smax[2], smax[3]));
    __syncthreads();
    m = sm_all;

    float e0 = __expf(v.x - m), e1 = __expf(v.y - m);
    float e2 = __expf(v.z - m), e3 = __expf(v.w - m);
    float s = e0 + e1 + e2 + e3;
    #pragma unroll
    for (int off = 32; off; off >>= 1) s += __shfl_down(s, off);
    __shared__ float ssum[4];
    __shared__ float ss_all;
    if (lane == 0) ssum[wave] = s;
    __syncthreads();
    if (tid == 0) ss_all = ssum[0] + ssum[1] + ssum[2] + ssum[3];
    __syncthreads();
    const float inv = 1.0f / ss_all;

    ((float4*)p)[tid] = make_float4(e0 * inv, e1 * inv, e2 * inv, e3 * inv);
}

// ---------------------------------------------------------------------------
extern "C" void kernel_launch(void* const* d_in, const int* in_sizes, int n_in,
                              void* d_out, int out_size, void* d_ws, size_t ws_size,
                              hipStream_t stream) {
    const float* src   = (const float*)d_in[0];  // (16,1024,512)
    const void*  maskp = d_in[1];                // (16,1024) bool/int32
    const float* query = (const float*)d_in[2];  // (512,16,256)
    const float* Wsrc  = (const float*)d_in[3];  // (512,1024)
    const float* wcomb = (const float*)d_in[4];  // (4,)
    float* out = (float*)d_out;                  // (512,16,1024)

    // workspace layout (total 50 MB + 256 B; Qh/Ql alias Ah/Al after gemm1)
    constexpr size_t MB = 1024 * 1024;
    char* ws = (char*)d_ws;
    int* flag = (int*)ws;
    f16* Ah  = (f16*)(ws + 256);
    f16* Al  = (f16*)(ws + 256 + 16 * MB);
    f16* Bht = (f16*)(ws + 256 + 32 * MB);
    f16* Blt = (f16*)(ws + 256 + 33 * MB);
    f16* Ch  = (f16*)(ws + 256 + 34 * MB);
    f16* Cl  = (f16*)(ws + 256 + 42 * MB);
    f16* Qh  = (f16*)(ws + 256);            // aliases Ah (free after gemm1)
    f16* Ql  = (f16*)(ws + 256 + 4 * MB);   // aliases Ah region

    detect_mask_kernel<<<1, 256, 0, stream>>>((const unsigned char*)maskp, flag);

    conv_a_kernel<<<(Mn * En) / (256 * 4), 256, 0, stream>>>(src, Ah, Al);
    {
        dim3 grid((Hn * QD) / 64, En / 64);  // (16, 8)
        conv_b_kernel<<<grid, 256, 0, stream>>>(Wsrc, Bht, Blt);
    }
    {
        dim3 grid(Mn / 128, QD / 32);        // (128, 8)
        gemm1_kernel<<<grid, 256, 0, stream>>>(Ah, Al, Bht, Blt, wcomb, Ch, Cl);
    }
    conv_q_kernel<<<(Tn * Bn) / 4, 256, 0, stream>>>(query, Qh, Ql);
    {
        dim3 grid(Sn / 128, Tn / 128, Bn);   // (8, 4, 16)
        gemm2_kernel<<<grid, 256, 0, stream>>>(Ch, Cl, Qh, Ql, maskp, wcomb, flag, out);
    }
    softmax_kernel<<<Tn * Bn, 256, 0, stream>>>(out);
}

// Round 5
// 166.582 us; speedup vs baseline: 2.3543x; 1.0636x over previous
//
#include <hip/hip_runtime.h>
#include <hip/hip_bf16.h>
#include <cstdint>

// Problem dims (fixed by reference setup_inputs)
constexpr int Bn = 16;    // batch
constexpr int Sn = 1024;  // source length
constexpr int Tn = 512;   // query steps
constexpr int QD = 256;   // query vec size
constexpr int En = 512;   // src encoding size
constexpr int Hn = 4;     // heads
constexpr float SLOPE = 0.01f;   // jax.nn.leaky_relu default
constexpr float NEG_INF = -1e9f;
constexpr int Mn = Bn * Sn;      // 16384 rows of the projection GEMM

typedef _Float16 f16;
typedef f16 f16x4 __attribute__((ext_vector_type(4)));
typedef f16 f16x8 __attribute__((ext_vector_type(8)));
typedef float f32x4 __attribute__((ext_vector_type(4)));

// async global->LDS, 16B per lane; dest = wave-uniform base + lane*16
#define G2L(g, l) __builtin_amdgcn_global_load_lds(                      \
    (const __attribute__((address_space(1))) void*)(g),                  \
    (__attribute__((address_space(3))) void*)(l), 16, 0, 0)

// ---------------------------------------------------------------------------
// K0: detect mask dtype (bool bytes vs int32) — writes flag (1 = int32) to ws
// ---------------------------------------------------------------------------
__global__ void detect_mask_kernel(const unsigned char* __restrict__ mask_bytes,
                                   int* __restrict__ flag) {
    __shared__ int cnt;
    if (threadIdx.x == 0) cnt = 0;
    __syncthreads();
    int local = 0;
    for (int p = threadIdx.x; p < 4096; p += 256) {
        if ((p & 3) != 0 && mask_bytes[p] != 0) local++;
    }
    atomicAdd(&cnt, local);
    __syncthreads();
    if (threadIdx.x == 0) flag[0] = (cnt == 0) ? 1 : 0;
}

// ---------------------------------------------------------------------------
// C1: split src (16384x512 f32) into Ah + Al (f16 row-major), exact hi/lo
// ---------------------------------------------------------------------------
__global__ __launch_bounds__(256) void conv_a_kernel(
    const float* __restrict__ src, f16* __restrict__ Ah, f16* __restrict__ Al)
{
    const size_t i4 = (size_t)blockIdx.x * 256 + threadIdx.x;
    const size_t base = i4 * 4;
    const float4 v = *(const float4*)(src + base);
    f16x4 hi, lo;
    const float xs[4] = {v.x, v.y, v.z, v.w};
    #pragma unroll
    for (int j = 0; j < 4; ++j) {
        f16 h = (f16)xs[j];
        hi[j] = h;
        lo[j] = (f16)(xs[j] - (float)h);
    }
    *(f16x4*)(Ah + base) = hi;
    *(f16x4*)(Al + base) = lo;
}

// ---------------------------------------------------------------------------
// C2: W (512x1024 f32) -> Bht, Blt (1024x512 f16) transposed + hi/lo split
// ---------------------------------------------------------------------------
__global__ __launch_bounds__(256) void conv_b_kernel(
    const float* __restrict__ W, f16* __restrict__ Bht, f16* __restrict__ Blt)
{
    __shared__ float T[64][65];
    const int tid = threadIdx.x;
    const int n0 = blockIdx.x * 64;
    const int k0 = blockIdx.y * 64;
    #pragma unroll
    for (int p = 0; p < 4; ++p) {
        const int e = p * 256 + tid;
        const int r = e >> 4;
        const int c4 = e & 15;
        const float4 v = *(const float4*)(W + (size_t)(k0 + r) * (Hn * QD) + n0 + c4 * 4);
        T[r][c4 * 4 + 0] = v.x; T[r][c4 * 4 + 1] = v.y;
        T[r][c4 * 4 + 2] = v.z; T[r][c4 * 4 + 3] = v.w;
    }
    __syncthreads();
    #pragma unroll
    for (int p = 0; p < 4; ++p) {
        const int e = p * 256 + tid;
        const int r = e >> 4;
        const int c4 = e & 15;
        f16x4 hi, lo;
        #pragma unroll
        for (int j = 0; j < 4; ++j) {
            const float x = T[c4 * 4 + j][r];
            f16 h = (f16)x;
            hi[j] = h;
            lo[j] = (f16)(x - (float)h);
        }
        const size_t off = (size_t)(n0 + r) * En + k0 + c4 * 4;
        *(f16x4*)(Bht + off) = hi;
        *(f16x4*)(Blt + off) = lo;
    }
}

// ---------------------------------------------------------------------------
// C3: split query (512,16,256) f32 -> Qh, Ql (b,t,q) f16.
// ---------------------------------------------------------------------------
__global__ __launch_bounds__(256) void conv_q_kernel(
    const float* __restrict__ query, f16* __restrict__ Qh, f16* __restrict__ Ql)
{
    const int tid = threadIdx.x;
    const int rloc = tid >> 6;
    const int lane = tid & 63;
    const int row = blockIdx.x * 4 + rloc;   // (t,b) pair, t-major
    const int t = row >> 4, b = row & 15;
    const float4 v = *(const float4*)(query + (size_t)row * QD + lane * 4);
    f16x4 hi, lo;
    const float xs[4] = {v.x, v.y, v.z, v.w};
    #pragma unroll
    for (int j = 0; j < 4; ++j) {
        f16 h = (f16)xs[j];
        hi[j] = h;
        lo[j] = (f16)(xs[j] - (float)h);
    }
    const size_t off = ((size_t)(b * Tn + t)) * QD + lane * 4;
    *(f16x4*)(Qh + off) = hi;
    *(f16x4*)(Ql + off) = lo;
}

// ---------------------------------------------------------------------------
// K1: 256x256-tile 8-phase pipelined f16-split MFMA GEMM.
//   C(16384 x 1024cols) where cols = [head4][q256]; block tile covers
//   256 rows x (64 q x 4 heads). K = 3 split-phases x 512 = 24 tiles of BK=64.
//   8 waves (2M x 4N), per-wave 128x64 output = 8 Mfrag x 4 Nfrag(=heads).
//   LDS ring: [buf(2)][A,B][ks(2)] units of 16 KB; 1 unit staged/phase;
//   vmcnt(6) at phases 3,7 (steady state); peeled last iter drains vmcnt(0).
// ---------------------------------------------------------------------------
#define VM6 asm volatile("s_waitcnt vmcnt(6)" ::: "memory")
#define VM0 asm volatile("s_waitcnt vmcnt(0)" ::: "memory")
#define VMX ((void)0)

__global__ __launch_bounds__(512, 2) void gemm1_kernel(
    const f16* __restrict__ Ah, const f16* __restrict__ Al,
    const f16* __restrict__ Bht, const f16* __restrict__ Blt,
    const float* __restrict__ wcomb,
    f16* __restrict__ Ch, f16* __restrict__ Cl)
{
    __shared__ f16 lds_f[65536];   // 128 KB: [buf2][A|B][ks2] units of 8192 f16

    const int tid = threadIdx.x;
    const int l  = tid & 63;
    const int wv = tid >> 6;         // 0..7
    const int wm = wv >> 2;          // 0..1  (M half)
    const int wn = wv & 3;           // 0..3  (q group)
    const int m0 = blockIdx.x * 256;
    const int q0 = blockIdx.y * 64;

    // --- staging per-thread constants: 2 chunks (16B-chunk index c) ---
    const int c0 = wv * 128 + l;
    const int c1 = c0 + 64;
    const int koff0 = c0 >> 8, row0 = c0 & 255;
    const int koff1 = c1 >> 8, row1 = c1 & 255;
    const int stgA0 = (m0 + row0) * En + koff0 * 8;
    const int stgA1 = (m0 + row1) * En + koff1 * 8;
    const int nB0 = ((row0 >> 4) & 3) * QD + q0 + (row0 >> 6) * 16 + (row0 & 15);
    const int nB1 = ((row1 >> 4) & 3) * QD + q0 + (row1 >> 6) * 16 + (row1 & 15);
    const int stgB0 = nB0 * En + koff0 * 8;
    const int stgB1 = nB1 * En + koff1 * 8;

    // --- fragment ds_read bases (f16 offsets); unit layout [koff4][row256][8]
    const int lA_base = (l >> 4) * 2048 + (wm * 128 + (l & 15)) * 8;
    const int lB_base = 16384 + (l >> 4) * 2048 + (wn * 64 + (l & 15)) * 8;

    f32x4 acc[8][4];
    #pragma unroll
    for (int m = 0; m < 8; ++m)
        #pragma unroll
        for (int h = 0; h < 4; ++h) acc[m][h] = (f32x4){0.f, 0.f, 0.f, 0.f};

    auto stage = [&](int t, int isB, int ks) {
        const f16* srcm;
        if (isB) srcm = (t < 16) ? Bht : Blt;
        else     srcm = (t < 8) ? Ah : ((t < 16) ? Al : Ah);
        const int kofs = (t & 7) * 64 + ks * 32;
        f16* lb = lds_f + (t & 1) * 32768 + (isB ? 16384 : 0) + ks * 8192 + wv * 1024;
        if (isB) {
            G2L(srcm + stgB0 + kofs, lb);
            G2L(srcm + stgB1 + kofs, lb + 512);
        } else {
            G2L(srcm + stgA0 + kofs, lb);
            G2L(srcm + stgA1 + kofs, lb + 512);
        }
    };

    f16x8 bf[4];

    // PH: one sub-phase. p in [0,4): ks_=p>>1 k-slice, mh_=p&1 M-half.
#define PH(p, rp, s_t, s_isB, s_ks, s_on, vmstmt)                             \
    {                                                                          \
        constexpr int ks_ = (p) >> 1, mh_ = (p) & 1;                           \
        const f16* Lb = lds_f + (rp) * 32768 + ks_ * 8192;                     \
        if (mh_ == 0) {                                                        \
            _Pragma("unroll")                                                  \
            for (int h = 0; h < 4; ++h)                                        \
                bf[h] = *(const f16x8*)(Lb + lB_base + h * 128);               \
        }                                                                      \
        f16x8 af[4];                                                           \
        _Pragma("unroll")                                                      \
        for (int m = 0; m < 4; ++m)                                            \
            af[m] = *(const f16x8*)(Lb + lA_base + (mh_ * 4 + m) * 128);       \
        if (s_on) stage(s_t, s_isB, s_ks);                                     \
        __builtin_amdgcn_s_barrier();                                          \
        asm volatile("s_waitcnt lgkmcnt(0)" ::: "memory");                     \
        __builtin_amdgcn_sched_barrier(0);                                     \
        __builtin_amdgcn_s_setprio(1);                                         \
        _Pragma("unroll")                                                      \
        for (int m = 0; m < 4; ++m) {                                          \
            _Pragma("unroll")                                                  \
            for (int h = 0; h < 4; ++h)                                        \
                acc[mh_ * 4 + m][h] = __builtin_amdgcn_mfma_f32_16x16x32_f16(  \
                    af[m], bf[h], acc[mh_ * 4 + m][h], 0, 0, 0);               \
        }                                                                      \
        __builtin_amdgcn_s_setprio(0);                                         \
        vmstmt;                                                                \
        __builtin_amdgcn_s_barrier();                                          \
    }

    // prologue: 7 units (tile0 complete + tile1 B0,A0,B1)
    stage(0, 1, 0);
    stage(0, 0, 0);
    stage(0, 1, 1);
    stage(0, 0, 1);
    stage(1, 1, 0);
    stage(1, 0, 0);
    stage(1, 1, 1);
    VM6;                       // tile0's 4 units landed
    __builtin_amdgcn_s_barrier();

    for (int i = 0; i < 11; ++i) {
        const int E = 2 * i, O = E + 1;
        // tile E from buf0
        PH(0, 0, O,     0, 1, true, VMX)   // stage O.A[ks1]
        PH(1, 0, E + 2, 1, 0, true, VMX)   // (E+2).B[ks0]
        PH(2, 0, E + 2, 0, 0, true, VMX)   // (E+2).A[ks0]
        PH(3, 0, E + 2, 1, 1, true, VM6)   // (E+2).B[ks1]; tile O complete
        // tile O from buf1
        PH(0, 1, E + 2, 0, 1, true, VMX)   // (E+2).A[ks1]
        PH(1, 1, O + 2, 1, 0, true, VMX)   // (O+2).B[ks0]
        PH(2, 1, O + 2, 0, 0, true, VMX)   // (O+2).A[ks0]
        PH(3, 1, O + 2, 1, 1, true, VM6)   // (O+2).B[ks1]; tile E+2 complete
    }
    // peeled last iteration (tiles 22, 23): only 23.A1 left to stage;
    // vmcnt(6) would NOT cover tile 23 here -> drain with vmcnt(0).
    {
        PH(0, 0, 23, 0, 1, true,  VMX)
        PH(1, 0, 0,  0, 0, false, VMX)
        PH(2, 0, 0,  0, 0, false, VMX)
        PH(3, 0, 0,  0, 0, false, VM0)     // tile 23 fully landed
        PH(0, 1, 0,  0, 0, false, VMX)
        PH(1, 1, 0,  0, 0, false, VMX)
        PH(2, 1, 0,  0, 0, false, VMX)
        PH(3, 1, 0,  0, 0, false, VMX)
    }
#undef PH

    // epilogue: leaky_relu + head combine + hi/lo split store
    const float w0 = wcomb[0], w1 = wcomb[1], w2 = wcomb[2], w3 = wcomb[3];
    const int q = q0 + wn * 16 + (l & 15);
    const int rbase = m0 + wm * 128 + (l >> 4) * 4;
    #pragma unroll
    for (int m = 0; m < 8; ++m) {
        #pragma unroll
        for (int i = 0; i < 4; ++i) {
            float x0 = acc[m][0][i]; x0 = x0 >= 0.f ? x0 : SLOPE * x0;
            float x1 = acc[m][1][i]; x1 = x1 >= 0.f ? x1 : SLOPE * x1;
            float x2 = acc[m][2][i]; x2 = x2 >= 0.f ? x2 : SLOPE * x2;
            float x3 = acc[m][3][i]; x3 = x3 >= 0.f ? x3 : SLOPE * x3;
            const float c = w0 * x0 + w1 * x1 + w2 * x2 + w3 * x3;
            const f16 ch = (f16)c;
            const f16 cl = (f16)(c - (float)ch);
            const size_t off = (size_t)(rbase + m * 16 + i) * QD + q;
            Ch[off] = ch;
            Cl[off] = cl;
        }
    }
}

// ---------------------------------------------------------------------------
// K2: out[t,b,s] = dot(combined[b,s,:], query[t,b,:]) via f16-split MFMA.
//   Per batch: M=1024(s) N=512(t) K=256. Phases Ch*Qh, Cl*Qh, Ch*Ql.
//   128x128 tile, BK=32, 24 steps, 2-phase double-buffered.
// ---------------------------------------------------------------------------
__global__ __launch_bounds__(256) void gemm2_kernel(
    const f16* __restrict__ Ch, const f16* __restrict__ Cl,
    const f16* __restrict__ Qh, const f16* __restrict__ Ql,
    const void* __restrict__ maskp, const float* __restrict__ wcomb,
    const int* __restrict__ flag,
    float* __restrict__ out)
{
    __shared__ f16 A0[4096], A1[4096], B0[4096], B1[4096];

    const int tid = threadIdx.x;
    const int l  = tid & 63;
    const int wv = tid >> 6;
    const int wr = wv >> 1, wcx = wv & 1;
    const int b  = blockIdx.z;
    const int s0 = blockIdx.x * 128;
    const int t0 = blockIdx.y * 128;

    const f16* Aps[3] = {Ch, Cl, Ch};
    const f16* Bps[3] = {Qh, Qh, Ql};

    const int rA = tid & 127;
    const int kA = (tid >> 7) * 8;
    const int colB = tid & 127;

    const int baseA = ((l >> 4) * 128 + wr * 64 + (l & 15)) * 8;
    const int baseB = ((l >> 4) * 128 + wcx * 64 + (l & 15)) * 8;

    f32x4 acc[4][4];
    #pragma unroll
    for (int m = 0; m < 4; ++m)
        #pragma unroll
        for (int n = 0; n < 4; ++n) acc[m][n] = (f32x4){0.f, 0.f, 0.f, 0.f};

    auto stage = [&](int t, f16* As, f16* Bs) {
        const int ph = t >> 3;
        const int k0 = (t & 7) * 32;
        const f16* ga = Aps[ph] + ((size_t)(b * Sn + s0 + rA)) * QD + kA + k0;
        const f16* gb = Bps[ph] + ((size_t)(b * Tn + t0 + colB)) * QD + kA + k0;
        G2L(ga,      As + wv * 512);
        G2L(ga + 16, As + 2048 + wv * 512);
        G2L(gb,      Bs + wv * 512);
        G2L(gb + 16, Bs + 2048 + wv * 512);
    };
    auto compute = [&](const f16* As, const f16* Bs) {
        f16x8 af[4], bf[4];
        #pragma unroll
        for (int m = 0; m < 4; ++m) af[m] = *(const f16x8*)(As + baseA + m * 128);
        #pragma unroll
        for (int n = 0; n < 4; ++n) bf[n] = *(const f16x8*)(Bs + baseB + n * 128);
        #pragma unroll
        for (int m = 0; m < 4; ++m)
            #pragma unroll
            for (int n = 0; n < 4; ++n)
                acc[m][n] = __builtin_amdgcn_mfma_f32_16x16x32_f16(
                    af[m], bf[n], acc[m][n], 0, 0, 0);
    };

    stage(0, A0, B0);
    __syncthreads();
    for (int t = 0; t < 24; t += 2) {
        stage(t + 1, A1, B1);
        compute(A0, B0);
        __syncthreads();
        if (t + 2 < 24) stage(t + 2, A0, B0);
        compute(A1, B1);
        __syncthreads();
    }

    const float sumw = wcomb[0] + wcomb[1] + wcomb[2] + wcomb[3];
    const float maskval = NEG_INF * sumw;
    const bool is_int = (flag[0] != 0);
    const int rbase = s0 + wr * 64 + (l >> 4) * 4;

    bool msk[4][4];
    #pragma unroll
    for (int m = 0; m < 4; ++m)
        #pragma unroll
        for (int i = 0; i < 4; ++i) {
            const int idx = b * Sn + rbase + m * 16 + i;
            int mm;
            if (is_int) mm = ((const int*)maskp)[idx];
            else        mm = (int)((const unsigned char*)maskp)[idx];
            msk[m][i] = (mm != 0);
        }

    #pragma unroll
    for (int m = 0; m < 4; ++m)
        #pragma unroll
        for (int n = 0; n < 4; ++n) {
            const int t = t0 + wcx * 64 + n * 16 + (l & 15);
            float vals[4];
            #pragma unroll
            for (int i = 0; i < 4; ++i)
                vals[i] = msk[m][i] ? maskval : acc[m][n][i];
            *(float4*)(out + ((size_t)t * Bn + b) * Sn + rbase + m * 16)
                = make_float4(vals[0], vals[1], vals[2], vals[3]);
        }
}

// ---------------------------------------------------------------------------
// K3: in-place softmax over last dim (S=1024). One block per (t,b) row.
// ---------------------------------------------------------------------------
__global__ __launch_bounds__(256) void softmax_kernel(float* __restrict__ out) {
    const size_t row = blockIdx.x;
    float* p = out + row * (size_t)Sn;
    const int tid = threadIdx.x;
    const int lane = tid & 63, wave = tid >> 6;

    float4 v = ((const float4*)p)[tid];

    float m = fmaxf(fmaxf(v.x, v.y), fmaxf(v.z, v.w));
    #pragma unroll
    for (int off = 32; off; off >>= 1) m = fmaxf(m, __shfl_down(m, off));
    __shared__ float smax[4];
    __shared__ float sm_all;
    if (lane == 0) smax[wave] = m;
    __syncthreads();
    if (tid == 0) sm_all = fmaxf(fmaxf(smax[0], smax[1]), fmaxf(smax[2], smax[3]));
    __syncthreads();
    m = sm_all;

    float e0 = __expf(v.x - m), e1 = __expf(v.y - m);
    float e2 = __expf(v.z - m), e3 = __expf(v.w - m);
    float s = e0 + e1 + e2 + e3;
    #pragma unroll
    for (int off = 32; off; off >>= 1) s += __shfl_down(s, off);
    __shared__ float ssum[4];
    __shared__ float ss_all;
    if (lane == 0) ssum[wave] = s;
    __syncthreads();
    if (tid == 0) ss_all = ssum[0] + ssum[1] + ssum[2] + ssum[3];
    __syncthreads();
    const float inv = 1.0f / ss_all;

    ((float4*)p)[tid] = make_float4(e0 * inv, e1 * inv, e2 * inv, e3 * inv);
}

// ---------------------------------------------------------------------------
extern "C" void kernel_launch(void* const* d_in, const int* in_sizes, int n_in,
                              void* d_out, int out_size, void* d_ws, size_t ws_size,
                              hipStream_t stream) {
    const float* src   = (const float*)d_in[0];  // (16,1024,512)
    const void*  maskp = d_in[1];                // (16,1024) bool/int32
    const float* query = (const float*)d_in[2];  // (512,16,256)
    const float* Wsrc  = (const float*)d_in[3];  // (512,1024)
    const float* wcomb = (const float*)d_in[4];  // (4,)
    float* out = (float*)d_out;                  // (512,16,1024)

    // workspace layout (total 50 MB + 256 B; Qh/Ql alias Ah/Al after gemm1)
    constexpr size_t MB = 1024 * 1024;
    char* ws = (char*)d_ws;
    int* flag = (int*)ws;
    f16* Ah  = (f16*)(ws + 256);
    f16* Al  = (f16*)(ws + 256 + 16 * MB);
    f16* Bht = (f16*)(ws + 256 + 32 * MB);
    f16* Blt = (f16*)(ws + 256 + 33 * MB);
    f16* Ch  = (f16*)(ws + 256 + 34 * MB);
    f16* Cl  = (f16*)(ws + 256 + 42 * MB);
    f16* Qh  = (f16*)(ws + 256);            // aliases Ah (free after gemm1)
    f16* Ql  = (f16*)(ws + 256 + 4 * MB);   // aliases Ah region

    detect_mask_kernel<<<1, 256, 0, stream>>>((const unsigned char*)maskp, flag);

    conv_a_kernel<<<(Mn * En) / (256 * 4), 256, 0, stream>>>(src, Ah, Al);
    {
        dim3 grid((Hn * QD) / 64, En / 64);  // (16, 8)
        conv_b_kernel<<<grid, 256, 0, stream>>>(Wsrc, Bht, Blt);
    }
    {
        dim3 grid(Mn / 256, QD / 64);        // (64, 4) = 256 blocks, 1/CU
        gemm1_kernel<<<grid, 512, 0, stream>>>(Ah, Al, Bht, Blt, wcomb, Ch, Cl);
    }
    conv_q_kernel<<<(Tn * Bn) / 4, 256, 0, stream>>>(query, Qh, Ql);
    {
        dim3 grid(Sn / 128, Tn / 128, Bn);   // (8, 4, 16)
        gemm2_kernel<<<grid, 256, 0, stream>>>(Ch, Cl, Qh, Ql, maskp, wcomb, flag, out);
    }
    softmax_kernel<<<Tn * Bn, 256, 0, stream>>>(out);
}

// Round 6
// 137.012 us; speedup vs baseline: 2.8624x; 1.2158x over previous
//
#include <hip/hip_runtime.h>
#include <hip/hip_bf16.h>
#include <cstdint>

// Problem dims (fixed by reference setup_inputs)
constexpr int Bn = 16;    // batch
constexpr int Sn = 1024;  // source length
constexpr int Tn = 512;   // query steps
constexpr int QD = 256;   // query vec size
constexpr int En = 512;   // src encoding size
constexpr int Hn = 4;     // heads
constexpr float SLOPE = 0.01f;   // jax.nn.leaky_relu default
constexpr float NEG_INF = -1e9f;
constexpr int Mn = Bn * Sn;      // 16384 rows of the projection GEMM

typedef _Float16 f16;
typedef f16 f16x4 __attribute__((ext_vector_type(4)));
typedef f16 f16x8 __attribute__((ext_vector_type(8)));
typedef float f32x4 __attribute__((ext_vector_type(4)));

// async global->LDS, 16B per lane; dest = wave-uniform base + lane*16
#define G2L(g, l) __builtin_amdgcn_global_load_lds(                      \
    (const __attribute__((address_space(1))) void*)(g),                  \
    (__attribute__((address_space(3))) void*)(l), 16, 0, 0)

// ---------------------------------------------------------------------------
// K0: detect mask dtype (bool bytes vs int32) — writes flag (1 = int32) to ws
// ---------------------------------------------------------------------------
__global__ void detect_mask_kernel(const unsigned char* __restrict__ mask_bytes,
                                   int* __restrict__ flag) {
    __shared__ int cnt;
    if (threadIdx.x == 0) cnt = 0;
    __syncthreads();
    int local = 0;
    for (int p = threadIdx.x; p < 4096; p += 256) {
        if ((p & 3) != 0 && mask_bytes[p] != 0) local++;
    }
    atomicAdd(&cnt, local);
    __syncthreads();
    if (threadIdx.x == 0) flag[0] = (cnt == 0) ? 1 : 0;
}

// ---------------------------------------------------------------------------
// C1: split src (16384x512 f32) into Ah + Al (f16 row-major), exact hi/lo
// ---------------------------------------------------------------------------
__global__ __launch_bounds__(256) void conv_a_kernel(
    const float* __restrict__ src, f16* __restrict__ Ah, f16* __restrict__ Al)
{
    const size_t i4 = (size_t)blockIdx.x * 256 + threadIdx.x;
    const size_t base = i4 * 4;
    const float4 v = *(const float4*)(src + base);
    f16x4 hi, lo;
    const float xs[4] = {v.x, v.y, v.z, v.w};
    #pragma unroll
    for (int j = 0; j < 4; ++j) {
        f16 h = (f16)xs[j];
        hi[j] = h;
        lo[j] = (f16)(xs[j] - (float)h);
    }
    *(f16x4*)(Ah + base) = hi;
    *(f16x4*)(Al + base) = lo;
}

// ---------------------------------------------------------------------------
// C2: W (512x1024 f32) -> Bht, Blt (1024x512 f16) transposed + hi/lo split
// ---------------------------------------------------------------------------
__global__ __launch_bounds__(256) void conv_b_kernel(
    const float* __restrict__ W, f16* __restrict__ Bht, f16* __restrict__ Blt)
{
    __shared__ float T[64][65];
    const int tid = threadIdx.x;
    const int n0 = blockIdx.x * 64;
    const int k0 = blockIdx.y * 64;
    #pragma unroll
    for (int p = 0; p < 4; ++p) {
        const int e = p * 256 + tid;
        const int r = e >> 4;
        const int c4 = e & 15;
        const float4 v = *(const float4*)(W + (size_t)(k0 + r) * (Hn * QD) + n0 + c4 * 4);
        T[r][c4 * 4 + 0] = v.x; T[r][c4 * 4 + 1] = v.y;
        T[r][c4 * 4 + 2] = v.z; T[r][c4 * 4 + 3] = v.w;
    }
    __syncthreads();
    #pragma unroll
    for (int p = 0; p < 4; ++p) {
        const int e = p * 256 + tid;
        const int r = e >> 4;
        const int c4 = e & 15;
        f16x4 hi, lo;
        #pragma unroll
        for (int j = 0; j < 4; ++j) {
            const float x = T[c4 * 4 + j][r];
            f16 h = (f16)x;
            hi[j] = h;
            lo[j] = (f16)(x - (float)h);
        }
        const size_t off = (size_t)(n0 + r) * En + k0 + c4 * 4;
        *(f16x4*)(Bht + off) = hi;
        *(f16x4*)(Blt + off) = lo;
    }
}

// ---------------------------------------------------------------------------
// C3: split query (512,16,256) f32 -> Qh, Ql (b,t,q) f16.
// ---------------------------------------------------------------------------
__global__ __launch_bounds__(256) void conv_q_kernel(
    const float* __restrict__ query, f16* __restrict__ Qh, f16* __restrict__ Ql)
{
    const int tid = threadIdx.x;
    const int rloc = tid >> 6;
    const int lane = tid & 63;
    const int row = blockIdx.x * 4 + rloc;   // (t,b) pair, t-major
    const int t = row >> 4, b = row & 15;
    const float4 v = *(const float4*)(query + (size_t)row * QD + lane * 4);
    f16x4 hi, lo;
    const float xs[4] = {v.x, v.y, v.z, v.w};
    #pragma unroll
    for (int j = 0; j < 4; ++j) {
        f16 h = (f16)xs[j];
        hi[j] = h;
        lo[j] = (f16)(xs[j] - (float)h);
    }
    const size_t off = ((size_t)(b * Tn + t)) * QD + lane * 4;
    *(f16x4*)(Qh + off) = hi;
    *(f16x4*)(Ql + off) = lo;
}

// ---------------------------------------------------------------------------
// K1: 256x256-tile 8-phase pipelined f16-split MFMA GEMM.
//   LDS unit = [row(256)][k(32)] f16 (64 B rows) -> staging G2L is
//   4-lanes-per-row fully-used 64B lines. 16B k-chunks XOR-permuted by
//   slot(row,k4) = global(row, k4 ^ ((row>>1)&3)) (involution applied at
//   per-lane G2L source AND at frag ds_read) to keep reads conflict-free.
//   Ring/vmcnt schedule identical to R5 (verified): vmcnt(6) at ph3/7,
//   peeled last iteration drains vmcnt(0).
// ---------------------------------------------------------------------------
#define VM6 asm volatile("s_waitcnt vmcnt(6)" ::: "memory")
#define VM0 asm volatile("s_waitcnt vmcnt(0)" ::: "memory")
#define VMX ((void)0)

__global__ __launch_bounds__(512, 2) void gemm1_kernel(
    const f16* __restrict__ Ah, const f16* __restrict__ Al,
    const f16* __restrict__ Bht, const f16* __restrict__ Blt,
    const float* __restrict__ wcomb,
    f16* __restrict__ Ch, f16* __restrict__ Cl)
{
    __shared__ f16 lds_f[65536];   // 128 KB: [buf2][A|B][ks2] units of 8192 f16

    const int tid = threadIdx.x;
    const int l  = tid & 63;
    const int wv = tid >> 6;         // 0..7
    const int wm = wv >> 2;          // 0..1  (M half)
    const int wn = wv & 3;           // 0..3  (q group)
    const int m0 = blockIdx.x * 256;
    const int q0 = blockIdx.y * 64;

    // --- staging per-thread constants: 2 chunks (16B-chunk index c) ---
    const int c0   = wv * 64 + l;        // 0..511 (instr2 adds 512)
    const int row0 = c0 >> 2;            // 0..127 (instr2: +128)
    const int k40  = c0 & 3;
    const int xk   = (k40 ^ ((row0 >> 1) & 3)) * 8;   // XOR'd k-chunk (f16)
    const int stgA0 = (m0 + row0) * En + xk;
    const int stgA1 = stgA0 + 128 * En;               // row+128: same XOR
    const int nB0r = ((row0 >> 4) & 3) * QD + q0 + (row0 >> 6) * 16 + (row0 & 15);
    const int stgB0 = nB0r * En + xk;
    const int stgB1 = stgB0 + 32 * En;                // col+128 -> nB+32, same XOR

    // --- fragment ds_read bases (f16, within a unit) ---
    const int xfr   = ((l & 15) >> 1) & 3;            // lane-constant XOR nibble
    const int aBase = (wm * 128 + (l & 15)) * 32 + (((l >> 4) ^ xfr)) * 8;
    const int bBase = (wn * 64  + (l & 15)) * 32 + (((l >> 4) ^ xfr)) * 8;

    f32x4 acc[8][4];
    #pragma unroll
    for (int m = 0; m < 8; ++m)
        #pragma unroll
        for (int h = 0; h < 4; ++h) acc[m][h] = (f32x4){0.f, 0.f, 0.f, 0.f};

    auto stage = [&](int t, int isB, int ks) {
        const f16* srcm;
        if (isB) srcm = (t < 16) ? Bht : Blt;
        else     srcm = (t < 8) ? Ah : ((t < 16) ? Al : Ah);
        const int kofs = (t & 7) * 64 + ks * 32;
        f16* lb = lds_f + (t & 1) * 32768 + (isB ? 16384 : 0) + ks * 8192 + wv * 512;
        if (isB) {
            G2L(srcm + stgB0 + kofs, lb);
            G2L(srcm + stgB1 + kofs, lb + 4096);
        } else {
            G2L(srcm + stgA0 + kofs, lb);
            G2L(srcm + stgA1 + kofs, lb + 4096);
        }
    };

    f16x8 bf[4];

    // PH: one sub-phase. p in [0,4): ks_=p>>1 k-slice, mh_=p&1 M-half.
#define PH(p, rp, s_t, s_isB, s_ks, s_on, vmstmt)                             \
    {                                                                          \
        constexpr int ks_ = (p) >> 1, mh_ = (p) & 1;                           \
        const f16* Lb = lds_f + (rp) * 32768 + ks_ * 8192;                     \
        if (mh_ == 0) {                                                        \
            _Pragma("unroll")                                                  \
            for (int h = 0; h < 4; ++h)                                        \
                bf[h] = *(const f16x8*)(Lb + 16384 + bBase + h * 512);         \
        }                                                                      \
        f16x8 af[4];                                                           \
        _Pragma("unroll")                                                      \
        for (int m = 0; m < 4; ++m)                                            \
            af[m] = *(const f16x8*)(Lb + aBase + (mh_ * 4 + m) * 512);         \
        if (s_on) stage(s_t, s_isB, s_ks);                                     \
        __builtin_amdgcn_s_barrier();                                          \
        asm volatile("s_waitcnt lgkmcnt(0)" ::: "memory");                     \
        __builtin_amdgcn_sched_barrier(0);                                     \
        __builtin_amdgcn_s_setprio(1);                                         \
        _Pragma("unroll")                                                      \
        for (int m = 0; m < 4; ++m) {                                          \
            _Pragma("unroll")                                                  \
            for (int h = 0; h < 4; ++h)                                        \
                acc[mh_ * 4 + m][h] = __builtin_amdgcn_mfma_f32_16x16x32_f16(  \
                    af[m], bf[h], acc[mh_ * 4 + m][h], 0, 0, 0);               \
        }                                                                      \
        __builtin_amdgcn_s_setprio(0);                                         \
        vmstmt;                                                                \
        __builtin_amdgcn_s_barrier();                                          \
    }

    // prologue: 7 units (tile0 complete + tile1 B0,A0,B1)
    stage(0, 1, 0);
    stage(0, 0, 0);
    stage(0, 1, 1);
    stage(0, 0, 1);
    stage(1, 1, 0);
    stage(1, 0, 0);
    stage(1, 1, 1);
    VM6;                       // tile0's 4 units landed
    __builtin_amdgcn_s_barrier();

    for (int i = 0; i < 11; ++i) {
        const int E = 2 * i, O = E + 1;
        // tile E from buf0
        PH(0, 0, O,     0, 1, true, VMX)   // stage O.A[ks1]
        PH(1, 0, E + 2, 1, 0, true, VMX)   // (E+2).B[ks0]
        PH(2, 0, E + 2, 0, 0, true, VMX)   // (E+2).A[ks0]
        PH(3, 0, E + 2, 1, 1, true, VM6)   // (E+2).B[ks1]; tile O complete
        // tile O from buf1
        PH(0, 1, E + 2, 0, 1, true, VMX)   // (E+2).A[ks1]
        PH(1, 1, O + 2, 1, 0, true, VMX)   // (O+2).B[ks0]
        PH(2, 1, O + 2, 0, 0, true, VMX)   // (O+2).A[ks0]
        PH(3, 1, O + 2, 1, 1, true, VM6)   // (O+2).B[ks1]; tile E+2 complete
    }
    // peeled last iteration (tiles 22, 23): only 23.A1 left to stage;
    // vmcnt(6) would NOT cover tile 23 here -> drain with vmcnt(0).
    {
        PH(0, 0, 23, 0, 1, true,  VMX)
        PH(1, 0, 0,  0, 0, false, VMX)
        PH(2, 0, 0,  0, 0, false, VMX)
        PH(3, 0, 0,  0, 0, false, VM0)     // tile 23 fully landed
        PH(0, 1, 0,  0, 0, false, VMX)
        PH(1, 1, 0,  0, 0, false, VMX)
        PH(2, 1, 0,  0, 0, false, VMX)
        PH(3, 1, 0,  0, 0, false, VMX)
    }
#undef PH

    // epilogue: leaky_relu + head combine + hi/lo split store
    const float w0 = wcomb[0], w1 = wcomb[1], w2 = wcomb[2], w3 = wcomb[3];
    const int q = q0 + wn * 16 + (l & 15);
    const int rbase = m0 + wm * 128 + (l >> 4) * 4;
    #pragma unroll
    for (int m = 0; m < 8; ++m) {
        #pragma unroll
        for (int i = 0; i < 4; ++i) {
            float x0 = acc[m][0][i]; x0 = x0 >= 0.f ? x0 : SLOPE * x0;
            float x1 = acc[m][1][i]; x1 = x1 >= 0.f ? x1 : SLOPE * x1;
            float x2 = acc[m][2][i]; x2 = x2 >= 0.f ? x2 : SLOPE * x2;
            float x3 = acc[m][3][i]; x3 = x3 >= 0.f ? x3 : SLOPE * x3;
            const float c = w0 * x0 + w1 * x1 + w2 * x2 + w3 * x3;
            const f16 ch = (f16)c;
            const f16 cl = (f16)(c - (float)ch);
            const size_t off = (size_t)(rbase + m * 16 + i) * QD + q;
            Ch[off] = ch;
            Cl[off] = cl;
        }
    }
}

// ---------------------------------------------------------------------------
// K2: out[t,b,s] = dot(combined[b,s,:], query[t,b,:]) via f16-split MFMA.
//   128x128 tile, BK=32, 24 steps, 2-phase double-buffered.
//   Same [row][k32] + XOR-chunk staging scheme as K1.
// ---------------------------------------------------------------------------
__global__ __launch_bounds__(256) void gemm2_kernel(
    const f16* __restrict__ Ch, const f16* __restrict__ Cl,
    const f16* __restrict__ Qh, const f16* __restrict__ Ql,
    const void* __restrict__ maskp, const float* __restrict__ wcomb,
    const int* __restrict__ flag,
    float* __restrict__ out)
{
    __shared__ f16 A0[4096], A1[4096], B0[4096], B1[4096];

    const int tid = threadIdx.x;
    const int l  = tid & 63;
    const int wv = tid >> 6;
    const int wr = wv >> 1, wcx = wv & 1;
    const int b  = blockIdx.z;
    const int s0 = blockIdx.x * 128;
    const int t0 = blockIdx.y * 128;

    const f16* Aps[3] = {Ch, Cl, Ch};
    const f16* Bps[3] = {Qh, Qh, Ql};

    // staging: chunk c = wv*64 + l (instr2: +256) of unit [row(128)][k(32)]
    const int c0   = wv * 64 + l;        // 0..255
    const int row0 = c0 >> 2;            // 0..63 (instr2: +64)
    const int k40  = c0 & 3;
    const int xk   = (k40 ^ ((row0 >> 1) & 3)) * 8;
    const int sA0  = (b * Sn + s0 + row0) * QD + xk;
    const int sA1  = sA0 + 64 * QD;
    const int sB0  = (b * Tn + t0 + row0) * QD + xk;
    const int sB1  = sB0 + 64 * QD;

    // fragment read bases
    const int xfr  = ((l & 15) >> 1) & 3;
    const int aB2  = (wr * 64  + (l & 15)) * 32 + (((l >> 4) ^ xfr)) * 8;
    const int bB2  = (wcx * 64 + (l & 15)) * 32 + (((l >> 4) ^ xfr)) * 8;

    f32x4 acc[4][4];
    #pragma unroll
    for (int m = 0; m < 4; ++m)
        #pragma unroll
        for (int n = 0; n < 4; ++n) acc[m][n] = (f32x4){0.f, 0.f, 0.f, 0.f};

    auto stage = [&](int t, f16* As, f16* Bs) {
        const int ph = t >> 3;
        const int kk = (t & 7) * 32;
        G2L(Aps[ph] + sA0 + kk, As + wv * 512);
        G2L(Aps[ph] + sA1 + kk, As + 2048 + wv * 512);
        G2L(Bps[ph] + sB0 + kk, Bs + wv * 512);
        G2L(Bps[ph] + sB1 + kk, Bs + 2048 + wv * 512);
    };
    auto compute = [&](const f16* As, const f16* Bs) {
        f16x8 af[4], bf[4];
        #pragma unroll
        for (int m = 0; m < 4; ++m) af[m] = *(const f16x8*)(As + aB2 + m * 512);
        #pragma unroll
        for (int n = 0; n < 4; ++n) bf[n] = *(const f16x8*)(Bs + bB2 + n * 512);
        #pragma unroll
        for (int m = 0; m < 4; ++m)
            #pragma unroll
            for (int n = 0; n < 4; ++n)
                acc[m][n] = __builtin_amdgcn_mfma_f32_16x16x32_f16(
                    af[m], bf[n], acc[m][n], 0, 0, 0);
    };

    stage(0, A0, B0);
    __syncthreads();
    for (int t = 0; t < 24; t += 2) {
        stage(t + 1, A1, B1);
        compute(A0, B0);
        __syncthreads();
        if (t + 2 < 24) stage(t + 2, A0, B0);
        compute(A1, B1);
        __syncthreads();
    }

    const float sumw = wcomb[0] + wcomb[1] + wcomb[2] + wcomb[3];
    const float maskval = NEG_INF * sumw;
    const bool is_int = (flag[0] != 0);
    const int rbase = s0 + wr * 64 + (l >> 4) * 4;

    bool msk[4][4];
    #pragma unroll
    for (int m = 0; m < 4; ++m)
        #pragma unroll
        for (int i = 0; i < 4; ++i) {
            const int idx = b * Sn + rbase + m * 16 + i;
            int mm;
            if (is_int) mm = ((const int*)maskp)[idx];
            else        mm = (int)((const unsigned char*)maskp)[idx];
            msk[m][i] = (mm != 0);
        }

    #pragma unroll
    for (int m = 0; m < 4; ++m)
        #pragma unroll
        for (int n = 0; n < 4; ++n) {
            const int t = t0 + wcx * 64 + n * 16 + (l & 15);
            float vals[4];
            #pragma unroll
            for (int i = 0; i < 4; ++i)
                vals[i] = msk[m][i] ? maskval : acc[m][n][i];
            *(float4*)(out + ((size_t)t * Bn + b) * Sn + rbase + m * 16)
                = make_float4(vals[0], vals[1], vals[2], vals[3]);
        }
}

// ---------------------------------------------------------------------------
// K3: in-place softmax over last dim (S=1024). One block per (t,b) row.
// ---------------------------------------------------------------------------
__global__ __launch_bounds__(256) void softmax_kernel(float* __restrict__ out) {
    const size_t row = blockIdx.x;
    float* p = out + row * (size_t)Sn;
    const int tid = threadIdx.x;
    const int lane = tid & 63, wave = tid >> 6;

    float4 v = ((const float4*)p)[tid];

    float m = fmaxf(fmaxf(v.x, v.y), fmaxf(v.z, v.w));
    #pragma unroll
    for (int off = 32; off; off >>= 1) m = fmaxf(m, __shfl_down(m, off));
    __shared__ float smax[4];
    __shared__ float sm_all;
    if (lane == 0) smax[wave] = m;
    __syncthreads();
    if (tid == 0) sm_all = fmaxf(fmaxf(smax[0], smax[1]), fmaxf(smax[2], smax[3]));
    __syncthreads();
    m = sm_all;

    float e0 = __expf(v.x - m), e1 = __expf(v.y - m);
    float e2 = __expf(v.z - m), e3 = __expf(v.w - m);
    float s = e0 + e1 + e2 + e3;
    #pragma unroll
    for (int off = 32; off; off >>= 1) s += __shfl_down(s, off);
    __shared__ float ssum[4];
    __shared__ float ss_all;
    if (lane == 0) ssum[wave] = s;
    __syncthreads();
    if (tid == 0) ss_all = ssum[0] + ssum[1] + ssum[2] + ssum[3];
    __syncthreads();
    const float inv = 1.0f / ss_all;

    ((float4*)p)[tid] = make_float4(e0 * inv, e1 * inv, e2 * inv, e3 * inv);
}

// ---------------------------------------------------------------------------
extern "C" void kernel_launch(void* const* d_in, const int* in_sizes, int n_in,
                              void* d_out, int out_size, void* d_ws, size_t ws_size,
                              hipStream_t stream) {
    const float* src   = (const float*)d_in[0];  // (16,1024,512)
    const void*  maskp = d_in[1];                // (16,1024) bool/int32
    const float* query = (const float*)d_in[2];  // (512,16,256)
    const float* Wsrc  = (const float*)d_in[3];  // (512,1024)
    const float* wcomb = (const float*)d_in[4];  // (4,)
    float* out = (float*)d_out;                  // (512,16,1024)

    // workspace layout (total 50 MB + 256 B; Qh/Ql alias Ah/Al after gemm1)
    constexpr size_t MB = 1024 * 1024;
    char* ws = (char*)d_ws;
    int* flag = (int*)ws;
    f16* Ah  = (f16*)(ws + 256);
    f16* Al  = (f16*)(ws + 256 + 16 * MB);
    f16* Bht = (f16*)(ws + 256 + 32 * MB);
    f16* Blt = (f16*)(ws + 256 + 33 * MB);
    f16* Ch  = (f16*)(ws + 256 + 34 * MB);
    f16* Cl  = (f16*)(ws + 256 + 42 * MB);
    f16* Qh  = (f16*)(ws + 256);            // aliases Ah (free after gemm1)
    f16* Ql  = (f16*)(ws + 256 + 4 * MB);   // aliases Ah region

    detect_mask_kernel<<<1, 256, 0, stream>>>((const unsigned char*)maskp, flag);

    conv_a_kernel<<<(Mn * En) / (256 * 4), 256, 0, stream>>>(src, Ah, Al);
    {
        dim3 grid((Hn * QD) / 64, En / 64);  // (16, 8)
        conv_b_kernel<<<grid, 256, 0, stream>>>(Wsrc, Bht, Blt);
    }
    {
        dim3 grid(Mn / 256, QD / 64);        // (64, 4) = 256 blocks, 1/CU
        gemm1_kernel<<<grid, 512, 0, stream>>>(Ah, Al, Bht, Blt, wcomb, Ch, Cl);
    }
    conv_q_kernel<<<(Tn * Bn) / 4, 256, 0, stream>>>(query, Qh, Ql);
    {
        dim3 grid(Sn / 128, Tn / 128, Bn);   // (8, 4, 16)
        gemm2_kernel<<<grid, 256, 0, stream>>>(Ch, Cl, Qh, Ql, maskp, wcomb, flag, out);
    }
    softmax_kernel<<<Tn * Bn, 256, 0, stream>>>(out);
}

// Round 7
// 128.555 us; speedup vs baseline: 3.0507x; 1.0658x over previous
//
#include <hip/hip_runtime.h>
#include <hip/hip_bf16.h>
#include <cstdint>

// Problem dims (fixed by reference setup_inputs)
constexpr int Bn = 16;    // batch
constexpr int Sn = 1024;  // source length
constexpr int Tn = 512;   // query steps
constexpr int QD = 256;   // query vec size
constexpr int En = 512;   // src encoding size
constexpr int Hn = 4;     // heads
constexpr float SLOPE = 0.01f;   // jax.nn.leaky_relu default
constexpr float NEG_INF = -1e9f;
constexpr int Mn = Bn * Sn;      // 16384 rows of the projection GEMM

typedef _Float16 f16;
typedef f16 f16x4 __attribute__((ext_vector_type(4)));
typedef f16 f16x8 __attribute__((ext_vector_type(8)));
typedef float f32x4 __attribute__((ext_vector_type(4)));

// async global->LDS, 16B per lane; dest = wave-uniform base + lane*16
#define G2L(g, l) __builtin_amdgcn_global_load_lds(                      \
    (const __attribute__((address_space(1))) void*)(g),                  \
    (__attribute__((address_space(3))) void*)(l), 16, 0, 0)

#define VM4 asm volatile("s_waitcnt vmcnt(4)" ::: "memory")
#define VM0 asm volatile("s_waitcnt vmcnt(0)" ::: "memory")

// ---------------------------------------------------------------------------
// K0: detect mask dtype (bool bytes vs int32) — writes flag (1 = int32) to ws
// ---------------------------------------------------------------------------
__global__ void detect_mask_kernel(const unsigned char* __restrict__ mask_bytes,
                                   int* __restrict__ flag) {
    __shared__ int cnt;
    if (threadIdx.x == 0) cnt = 0;
    __syncthreads();
    int local = 0;
    for (int p = threadIdx.x; p < 4096; p += 256) {
        if ((p & 3) != 0 && mask_bytes[p] != 0) local++;
    }
    atomicAdd(&cnt, local);
    __syncthreads();
    if (threadIdx.x == 0) flag[0] = (cnt == 0) ? 1 : 0;
}

// ---------------------------------------------------------------------------
// C1: split src (16384x512 f32) into Ah + Al (f16 row-major), exact hi/lo
// ---------------------------------------------------------------------------
__global__ __launch_bounds__(256) void conv_a_kernel(
    const float* __restrict__ src, f16* __restrict__ Ah, f16* __restrict__ Al)
{
    const size_t i4 = (size_t)blockIdx.x * 256 + threadIdx.x;
    const size_t base = i4 * 4;
    const float4 v = *(const float4*)(src + base);
    f16x4 hi, lo;
    const float xs[4] = {v.x, v.y, v.z, v.w};
    #pragma unroll
    for (int j = 0; j < 4; ++j) {
        f16 h = (f16)xs[j];
        hi[j] = h;
        lo[j] = (f16)(xs[j] - (float)h);
    }
    *(f16x4*)(Ah + base) = hi;
    *(f16x4*)(Al + base) = lo;
}

// ---------------------------------------------------------------------------
// C2: W (512x1024 f32) -> Bht, Blt (1024x512 f16) transposed + hi/lo split
// ---------------------------------------------------------------------------
__global__ __launch_bounds__(256) void conv_b_kernel(
    const float* __restrict__ W, f16* __restrict__ Bht, f16* __restrict__ Blt)
{
    __shared__ float T[64][65];
    const int tid = threadIdx.x;
    const int n0 = blockIdx.x * 64;
    const int k0 = blockIdx.y * 64;
    #pragma unroll
    for (int p = 0; p < 4; ++p) {
        const int e = p * 256 + tid;
        const int r = e >> 4;
        const int c4 = e & 15;
        const float4 v = *(const float4*)(W + (size_t)(k0 + r) * (Hn * QD) + n0 + c4 * 4);
        T[r][c4 * 4 + 0] = v.x; T[r][c4 * 4 + 1] = v.y;
        T[r][c4 * 4 + 2] = v.z; T[r][c4 * 4 + 3] = v.w;
    }
    __syncthreads();
    #pragma unroll
    for (int p = 0; p < 4; ++p) {
        const int e = p * 256 + tid;
        const int r = e >> 4;
        const int c4 = e & 15;
        f16x4 hi, lo;
        #pragma unroll
        for (int j = 0; j < 4; ++j) {
            const float x = T[c4 * 4 + j][r];
            f16 h = (f16)x;
            hi[j] = h;
            lo[j] = (f16)(x - (float)h);
        }
        const size_t off = (size_t)(n0 + r) * En + k0 + c4 * 4;
        *(f16x4*)(Bht + off) = hi;
        *(f16x4*)(Blt + off) = lo;
    }
}

// ---------------------------------------------------------------------------
// C3: split query (512,16,256) f32 -> Qh, Ql (b,t,q) f16.
// ---------------------------------------------------------------------------
__global__ __launch_bounds__(256) void conv_q_kernel(
    const float* __restrict__ query, f16* __restrict__ Qh, f16* __restrict__ Ql)
{
    const int tid = threadIdx.x;
    const int rloc = tid >> 6;
    const int lane = tid & 63;
    const int row = blockIdx.x * 4 + rloc;   // (t,b) pair, t-major
    const int t = row >> 4, b = row & 15;
    const float4 v = *(const float4*)(query + (size_t)row * QD + lane * 4);
    f16x4 hi, lo;
    const float xs[4] = {v.x, v.y, v.z, v.w};
    #pragma unroll
    for (int j = 0; j < 4; ++j) {
        f16 h = (f16)xs[j];
        hi[j] = h;
        lo[j] = (f16)(xs[j] - (float)h);
    }
    const size_t off = ((size_t)(b * Tn + t)) * QD + lane * 4;
    *(f16x4*)(Qh + off) = hi;
    *(f16x4*)(Ql + off) = lo;
}

// ---------------------------------------------------------------------------
// K1: 128x128-tile, BK=32, ring-3 pipelined f16-split MFMA GEMM.
//   48 K-tiles (3 split-phases x 16). 4 waves (2M x 2N), per-wave 64x64
//   (4 m-frags x 4 heads), 16 MFMA per phase. LDS 48 KB -> 3 blocks/CU.
//   Stage lead-2 (phase t stages tile t+2), vmcnt(4) per phase.
//   XOR-chunk scheme (validated R6): slot k4 = global k4 ^ ((row>>1)&3).
// ---------------------------------------------------------------------------
__global__ __launch_bounds__(256) void gemm1_kernel(
    const f16* __restrict__ Ah, const f16* __restrict__ Al,
    const f16* __restrict__ Bht, const f16* __restrict__ Blt,
    const float* __restrict__ wcomb,
    f16* __restrict__ Ch, f16* __restrict__ Cl)
{
    __shared__ f16 lds_f[24576];   // 3 slots x (A 4096 + B 4096) f16 = 48 KB

    const int tid = threadIdx.x;
    const int l  = tid & 63;
    const int wv = tid >> 6;         // 0..3
    const int wm = wv >> 1;          // M half (64 rows)
    const int wn = wv & 1;           // q-block (16 q)
    const int m0 = blockIdx.x * 128;
    const int q0 = blockIdx.y * 32;

    // staging constants: chunk c = tid (instr2: +256); row = c>>2, k4 = c&3
    const int rowc = tid >> 2;            // 0..63
    const int xk   = ((tid & 3) ^ ((rowc >> 1) & 3)) * 8;
    const int stgA = (m0 + rowc) * En + xk;                    // +64*En for instr2
    const int nB   = ((rowc >> 4) & 3) * QD + q0 + (rowc & 15); // qblk0; +16 for instr2
    const int stgB = nB * En + xk;

    // fragment ds_read bases (f16 idx); xor nibble lane-constant
    const int xf  = ((l >> 1) & 3);
    const int aFrag = (wm * 64 + (l & 15)) * 32 + (((l >> 4) ^ xf) * 8);
    const int bFrag = 4096 + (wn * 64 + (l & 15)) * 32 + (((l >> 4) ^ xf) * 8);

    f32x4 acc[4][4];
    #pragma unroll
    for (int m = 0; m < 4; ++m)
        #pragma unroll
        for (int h = 0; h < 4; ++h) acc[m][h] = (f32x4){0.f, 0.f, 0.f, 0.f};

    auto stage1 = [&](int t) {
        const f16* As = (t < 16) ? Ah : ((t < 32) ? Al : Ah);
        const f16* Bs = (t < 32) ? Bht : Blt;
        const int kofs = (t & 15) * 32;
        f16* dst = lds_f + (t % 3) * 8192 + wv * 512;
        G2L(As + stgA + kofs,           dst);
        G2L(As + stgA + 64 * En + kofs, dst + 2048);
        G2L(Bs + stgB + kofs,           dst + 4096);
        G2L(Bs + stgB + 16 * En + kofs, dst + 4096 + 2048);
    };

    // prologue: tiles 0,1 staged; wait tile0 (4 of tile1 outstanding)
    stage1(0);
    stage1(1);
    VM4;
    __builtin_amdgcn_s_barrier();

    #pragma unroll
    for (int t = 0; t < 48; ++t) {
        const f16* Lb = lds_f + (t % 3) * 8192;
        f16x8 af[4], bfr[4];
        #pragma unroll
        for (int m = 0; m < 4; ++m) af[m] = *(const f16x8*)(Lb + aFrag + m * 512);
        #pragma unroll
        for (int h = 0; h < 4; ++h) bfr[h] = *(const f16x8*)(Lb + bFrag + h * 512);
        if (t + 2 < 48) stage1(t + 2);
        __builtin_amdgcn_s_barrier();
        asm volatile("s_waitcnt lgkmcnt(0)" ::: "memory");
        __builtin_amdgcn_sched_barrier(0);
        __builtin_amdgcn_s_setprio(1);
        #pragma unroll
        for (int m = 0; m < 4; ++m) {
            #pragma unroll
            for (int h = 0; h < 4; ++h)
                acc[m][h] = __builtin_amdgcn_mfma_f32_16x16x32_f16(
                    af[m], bfr[h], acc[m][h], 0, 0, 0);
        }
        __builtin_amdgcn_s_setprio(0);
        if (t <= 45)      VM4;   // tile t+1 landed (tile t+2's 4 remain)
        else if (t == 46) VM0;   // drain: tile 47 landed
        __builtin_amdgcn_s_barrier();
    }

    // epilogue: leaky_relu + head combine + hi/lo split store
    const float w0 = wcomb[0], w1 = wcomb[1], w2 = wcomb[2], w3 = wcomb[3];
    const int q = q0 + wn * 16 + (l & 15);
    const int rbase = m0 + wm * 64 + (l >> 4) * 4;
    #pragma unroll
    for (int m = 0; m < 4; ++m) {
        #pragma unroll
        for (int i = 0; i < 4; ++i) {
            float x0 = acc[m][0][i]; x0 = x0 >= 0.f ? x0 : SLOPE * x0;
            float x1 = acc[m][1][i]; x1 = x1 >= 0.f ? x1 : SLOPE * x1;
            float x2 = acc[m][2][i]; x2 = x2 >= 0.f ? x2 : SLOPE * x2;
            float x3 = acc[m][3][i]; x3 = x3 >= 0.f ? x3 : SLOPE * x3;
            const float c = w0 * x0 + w1 * x1 + w2 * x2 + w3 * x3;
            const f16 ch = (f16)c;
            const f16 cl = (f16)(c - (float)ch);
            const size_t off = (size_t)(rbase + m * 16 + i) * QD + q;
            Ch[off] = ch;
            Cl[off] = cl;
        }
    }
}

// ---------------------------------------------------------------------------
// K2: out[t,b,s] = dot(combined[b,s,:], query[t,b,:]) via the same template.
//   Per batch M=1024(s) N=512(t) K=256x3. 128x128 tile, BK=32, ring-3,
//   24 K-tiles, 4 waves (2M x 2N), 16 MFMA/phase, vmcnt(4).
// ---------------------------------------------------------------------------
__global__ __launch_bounds__(256) void gemm2_kernel(
    const f16* __restrict__ Ch, const f16* __restrict__ Cl,
    const f16* __restrict__ Qh, const f16* __restrict__ Ql,
    const void* __restrict__ maskp, const float* __restrict__ wcomb,
    const int* __restrict__ flag,
    float* __restrict__ out)
{
    __shared__ f16 lds2[24576];   // 3 slots x (A 4096 + B 4096) f16

    const int tid = threadIdx.x;
    const int l  = tid & 63;
    const int wv = tid >> 6;
    const int wm = wv >> 1;          // s half
    const int wn = wv & 1;           // t half
    const int b  = blockIdx.z;
    const int s0 = blockIdx.x * 128;
    const int t0 = blockIdx.y * 128;

    // staging: chunk c = tid (instr2 +256); row = c>>2 (0..63; +64 instr2)
    const int rowc = tid >> 2;
    const int xk   = ((tid & 3) ^ ((rowc >> 1) & 3)) * 8;
    const int stgA = (b * Sn + s0 + rowc) * QD + xk;   // +64*QD instr2
    const int stgB = (b * Tn + t0 + rowc) * QD + xk;   // +64*QD instr2

    const int xf  = ((l >> 1) & 3);
    const int aFrag = (wm * 64 + (l & 15)) * 32 + (((l >> 4) ^ xf) * 8);
    const int bFrag = 4096 + (wn * 64 + (l & 15)) * 32 + (((l >> 4) ^ xf) * 8);

    f32x4 acc[4][4];
    #pragma unroll
    for (int m = 0; m < 4; ++m)
        #pragma unroll
        for (int n = 0; n < 4; ++n) acc[m][n] = (f32x4){0.f, 0.f, 0.f, 0.f};

    auto stage1 = [&](int t) {
        const f16* As = (t < 8) ? Ch : ((t < 16) ? Cl : Ch);
        const f16* Bs = (t < 16) ? Qh : Ql;
        const int kofs = (t & 7) * 32;
        f16* dst = lds2 + (t % 3) * 8192 + wv * 512;
        G2L(As + stgA + kofs,           dst);
        G2L(As + stgA + 64 * QD + kofs, dst + 2048);
        G2L(Bs + stgB + kofs,           dst + 4096);
        G2L(Bs + stgB + 64 * QD + kofs, dst + 4096 + 2048);
    };

    stage1(0);
    stage1(1);
    VM4;
    __builtin_amdgcn_s_barrier();

    #pragma unroll
    for (int kt = 0; kt < 24; ++kt) {
        const f16* Lb = lds2 + (kt % 3) * 8192;
        f16x8 af[4], bfr[4];
        #pragma unroll
        for (int m = 0; m < 4; ++m) af[m] = *(const f16x8*)(Lb + aFrag + m * 512);
        #pragma unroll
        for (int n = 0; n < 4; ++n) bfr[n] = *(const f16x8*)(Lb + bFrag + n * 512);
        if (kt + 2 < 24) stage1(kt + 2);
        __builtin_amdgcn_s_barrier();
        asm volatile("s_waitcnt lgkmcnt(0)" ::: "memory");
        __builtin_amdgcn_sched_barrier(0);
        __builtin_amdgcn_s_setprio(1);
        #pragma unroll
        for (int m = 0; m < 4; ++m) {
            #pragma unroll
            for (int n = 0; n < 4; ++n)
                acc[m][n] = __builtin_amdgcn_mfma_f32_16x16x32_f16(
                    af[m], bfr[n], acc[m][n], 0, 0, 0);
        }
        __builtin_amdgcn_s_setprio(0);
        if (kt <= 21)      VM4;
        else if (kt == 22) VM0;
        __builtin_amdgcn_s_barrier();
    }

    // epilogue: mask override + coalesced float4 stores along s
    const float sumw = wcomb[0] + wcomb[1] + wcomb[2] + wcomb[3];
    const float maskval = NEG_INF * sumw;
    const bool is_int = (flag[0] != 0);
    const int rbase = s0 + wm * 64 + (l >> 4) * 4;

    bool msk[4][4];
    #pragma unroll
    for (int m = 0; m < 4; ++m)
        #pragma unroll
        for (int i = 0; i < 4; ++i) {
            const int idx = b * Sn + rbase + m * 16 + i;
            int mm;
            if (is_int) mm = ((const int*)maskp)[idx];
            else        mm = (int)((const unsigned char*)maskp)[idx];
            msk[m][i] = (mm != 0);
        }

    #pragma unroll
    for (int m = 0; m < 4; ++m)
        #pragma unroll
        for (int n = 0; n < 4; ++n) {
            const int t = t0 + wn * 64 + n * 16 + (l & 15);
            float vals[4];
            #pragma unroll
            for (int i = 0; i < 4; ++i)
                vals[i] = msk[m][i] ? maskval : acc[m][n][i];
            *(float4*)(out + ((size_t)t * Bn + b) * Sn + rbase + m * 16)
                = make_float4(vals[0], vals[1], vals[2], vals[3]);
        }
}

// ---------------------------------------------------------------------------
// K3: in-place softmax over last dim (S=1024). One block per (t,b) row.
// ---------------------------------------------------------------------------
__global__ __launch_bounds__(256) void softmax_kernel(float* __restrict__ out) {
    const size_t row = blockIdx.x;
    float* p = out + row * (size_t)Sn;
    const int tid = threadIdx.x;
    const int lane = tid & 63, wave = tid >> 6;

    float4 v = ((const float4*)p)[tid];

    float m = fmaxf(fmaxf(v.x, v.y), fmaxf(v.z, v.w));
    #pragma unroll
    for (int off = 32; off; off >>= 1) m = fmaxf(m, __shfl_down(m, off));
    __shared__ float smax[4];
    __shared__ float sm_all;
    if (lane == 0) smax[wave] = m;
    __syncthreads();
    if (tid == 0) sm_all = fmaxf(fmaxf(smax[0], smax[1]), fmaxf(smax[2], smax[3]));
    __syncthreads();
    m = sm_all;

    float e0 = __expf(v.x - m), e1 = __expf(v.y - m);
    float e2 = __expf(v.z - m), e3 = __expf(v.w - m);
    float s = e0 + e1 + e2 + e3;
    #pragma unroll
    for (int off = 32; off; off >>= 1) s += __shfl_down(s, off);
    __shared__ float ssum[4];
    __shared__ float ss_all;
    if (lane == 0) ssum[wave] = s;
    __syncthreads();
    if (tid == 0) ss_all = ssum[0] + ssum[1] + ssum[2] + ssum[3];
    __syncthreads();
    const float inv = 1.0f / ss_all;

    ((float4*)p)[tid] = make_float4(e0 * inv, e1 * inv, e2 * inv, e3 * inv);
}

// ---------------------------------------------------------------------------
extern "C" void kernel_launch(void* const* d_in, const int* in_sizes, int n_in,
                              void* d_out, int out_size, void* d_ws, size_t ws_size,
                              hipStream_t stream) {
    const float* src   = (const float*)d_in[0];  // (16,1024,512)
    const void*  maskp = d_in[1];                // (16,1024) bool/int32
    const float* query = (const float*)d_in[2];  // (512,16,256)
    const float* Wsrc  = (const float*)d_in[3];  // (512,1024)
    const float* wcomb = (const float*)d_in[4];  // (4,)
    float* out = (float*)d_out;                  // (512,16,1024)

    // workspace layout (total 50 MB + 256 B; Qh/Ql alias Ah/Al after gemm1)
    constexpr size_t MB = 1024 * 1024;
    char* ws = (char*)d_ws;
    int* flag = (int*)ws;
    f16* Ah  = (f16*)(ws + 256);
    f16* Al  = (f16*)(ws + 256 + 16 * MB);
    f16* Bht = (f16*)(ws + 256 + 32 * MB);
    f16* Blt = (f16*)(ws + 256 + 33 * MB);
    f16* Ch  = (f16*)(ws + 256 + 34 * MB);
    f16* Cl  = (f16*)(ws + 256 + 42 * MB);
    f16* Qh  = (f16*)(ws + 256);            // aliases Ah (free after gemm1)
    f16* Ql  = (f16*)(ws + 256 + 4 * MB);   // aliases Ah region

    detect_mask_kernel<<<1, 256, 0, stream>>>((const unsigned char*)maskp, flag);

    conv_a_kernel<<<(Mn * En) / (256 * 4), 256, 0, stream>>>(src, Ah, Al);
    {
        dim3 grid((Hn * QD) / 64, En / 64);  // (16, 8)
        conv_b_kernel<<<grid, 256, 0, stream>>>(Wsrc, Bht, Blt);
    }
    {
        dim3 grid(Mn / 128, QD / 32);        // (128, 8) = 1024 blocks
        gemm1_kernel<<<grid, 256, 0, stream>>>(Ah, Al, Bht, Blt, wcomb, Ch, Cl);
    }
    conv_q_kernel<<<(Tn * Bn) / 4, 256, 0, stream>>>(query, Qh, Ql);
    {
        dim3 grid(Sn / 128, Tn / 128, Bn);   // (8, 4, 16) = 512 blocks
        gemm2_kernel<<<grid, 256, 0, stream>>>(Ch, Cl, Qh, Ql, maskp, wcomb, flag, out);
    }
    softmax_kernel<<<Tn * Bn, 256, 0, stream>>>(out);
}

// Round 8
// 121.958 us; speedup vs baseline: 3.2157x; 1.0541x over previous
//
#include <hip/hip_runtime.h>
#include <hip/hip_bf16.h>
#include <cstdint>

// Problem dims (fixed by reference setup_inputs)
constexpr int Bn = 16;    // batch
constexpr int Sn = 1024;  // source length
constexpr int Tn = 512;   // query steps
constexpr int QD = 256;   // query vec size
constexpr int En = 512;   // src encoding size
constexpr int Hn = 4;     // heads
constexpr float SLOPE = 0.01f;   // jax.nn.leaky_relu default
constexpr float NEG_INF = -1e9f;
constexpr int Mn = Bn * Sn;      // 16384 rows of the projection GEMM

typedef _Float16 f16;
typedef f16 f16x4 __attribute__((ext_vector_type(4)));
typedef f16 f16x8 __attribute__((ext_vector_type(8)));
typedef float f32x4 __attribute__((ext_vector_type(4)));

// async global->LDS, 16B per lane; dest = wave-uniform base + lane*16
#define G2L(g, l) __builtin_amdgcn_global_load_lds(                      \
    (const __attribute__((address_space(1))) void*)(g),                  \
    (__attribute__((address_space(3))) void*)(l), 16, 0, 0)

#define VM6 asm volatile("s_waitcnt vmcnt(6)" ::: "memory")
#define VM4 asm volatile("s_waitcnt vmcnt(4)" ::: "memory")
#define VM0 asm volatile("s_waitcnt vmcnt(0)" ::: "memory")

// ---------------------------------------------------------------------------
// K0: detect mask dtype (bool bytes vs int32) — writes flag (1 = int32) to ws
// ---------------------------------------------------------------------------
__global__ void detect_mask_kernel(const unsigned char* __restrict__ mask_bytes,
                                   int* __restrict__ flag) {
    __shared__ int cnt;
    if (threadIdx.x == 0) cnt = 0;
    __syncthreads();
    int local = 0;
    for (int p = threadIdx.x; p < 4096; p += 256) {
        if ((p & 3) != 0 && mask_bytes[p] != 0) local++;
    }
    atomicAdd(&cnt, local);
    __syncthreads();
    if (threadIdx.x == 0) flag[0] = (cnt == 0) ? 1 : 0;
}

// ---------------------------------------------------------------------------
// C1: split src (16384x512 f32) into Ah + Al (f16 row-major), exact hi/lo
// ---------------------------------------------------------------------------
__global__ __launch_bounds__(256) void conv_a_kernel(
    const float* __restrict__ src, f16* __restrict__ Ah, f16* __restrict__ Al)
{
    const size_t i4 = (size_t)blockIdx.x * 256 + threadIdx.x;
    const size_t base = i4 * 4;
    const float4 v = *(const float4*)(src + base);
    f16x4 hi, lo;
    const float xs[4] = {v.x, v.y, v.z, v.w};
    #pragma unroll
    for (int j = 0; j < 4; ++j) {
        f16 h = (f16)xs[j];
        hi[j] = h;
        lo[j] = (f16)(xs[j] - (float)h);
    }
    *(f16x4*)(Ah + base) = hi;
    *(f16x4*)(Al + base) = lo;
}

// ---------------------------------------------------------------------------
// C2: W (512x1024 f32) -> Bht, Blt (1024x512 f16) transposed + hi/lo split
// ---------------------------------------------------------------------------
__global__ __launch_bounds__(256) void conv_b_kernel(
    const float* __restrict__ W, f16* __restrict__ Bht, f16* __restrict__ Blt)
{
    __shared__ float T[64][65];
    const int tid = threadIdx.x;
    const int n0 = blockIdx.x * 64;
    const int k0 = blockIdx.y * 64;
    #pragma unroll
    for (int p = 0; p < 4; ++p) {
        const int e = p * 256 + tid;
        const int r = e >> 4;
        const int c4 = e & 15;
        const float4 v = *(const float4*)(W + (size_t)(k0 + r) * (Hn * QD) + n0 + c4 * 4);
        T[r][c4 * 4 + 0] = v.x; T[r][c4 * 4 + 1] = v.y;
        T[r][c4 * 4 + 2] = v.z; T[r][c4 * 4 + 3] = v.w;
    }
    __syncthreads();
    #pragma unroll
    for (int p = 0; p < 4; ++p) {
        const int e = p * 256 + tid;
        const int r = e >> 4;
        const int c4 = e & 15;
        f16x4 hi, lo;
        #pragma unroll
        for (int j = 0; j < 4; ++j) {
            const float x = T[c4 * 4 + j][r];
            f16 h = (f16)x;
            hi[j] = h;
            lo[j] = (f16)(x - (float)h);
        }
        const size_t off = (size_t)(n0 + r) * En + k0 + c4 * 4;
        *(f16x4*)(Bht + off) = hi;
        *(f16x4*)(Blt + off) = lo;
    }
}

// ---------------------------------------------------------------------------
// C3: split query (512,16,256) f32 -> Qh, Ql (b,t,q) f16.
// ---------------------------------------------------------------------------
__global__ __launch_bounds__(256) void conv_q_kernel(
    const float* __restrict__ query, f16* __restrict__ Qh, f16* __restrict__ Ql)
{
    const int tid = threadIdx.x;
    const int rloc = tid >> 6;
    const int lane = tid & 63;
    const int row = blockIdx.x * 4 + rloc;   // (t,b) pair, t-major
    const int t = row >> 4, b = row & 15;
    const float4 v = *(const float4*)(query + (size_t)row * QD + lane * 4);
    f16x4 hi, lo;
    const float xs[4] = {v.x, v.y, v.z, v.w};
    #pragma unroll
    for (int j = 0; j < 4; ++j) {
        f16 h = (f16)xs[j];
        hi[j] = h;
        lo[j] = (f16)(xs[j] - (float)h);
    }
    const size_t off = ((size_t)(b * Tn + t)) * QD + lane * 4;
    *(f16x4*)(Qh + off) = hi;
    *(f16x4*)(Ql + off) = lo;
}

// ---------------------------------------------------------------------------
// K1: 128(rows) x 256(cols = 64q x 4heads) tile, BK=32, ring-3 pipelined
//   f16-split MFMA GEMM. 48 K-tiles (3 split-phases x 16). 4 waves (2M x 2N),
//   per-wave 64x128 (4 m-frags x 8 col-frags) = 32 MFMA/phase.
//   LDS slot = A(4096 f16) + B(8192 f16) = 24 KB; ring-3 = 72 KB -> 2 blk/CU.
//   Stage lead-2, 6 G2L/thread/phase -> vmcnt(6); tail drains VM0 at t=46.
//   XOR-chunk scheme (validated R6/R7): slot k4 = global k4 ^ ((row>>1)&3).
// ---------------------------------------------------------------------------
__global__ __launch_bounds__(256) void gemm1_kernel(
    const f16* __restrict__ Ah, const f16* __restrict__ Al,
    const f16* __restrict__ Bht, const f16* __restrict__ Blt,
    const float* __restrict__ wcomb,
    f16* __restrict__ Ch, f16* __restrict__ Cl)
{
    __shared__ f16 lds_f[36864];   // 3 slots x 12288 f16 = 72 KB

    const int tid = threadIdx.x;
    const int l  = tid & 63;
    const int wv = tid >> 6;         // 0..3
    const int wm = wv >> 1;          // M half (64 rows)
    const int wn = wv & 1;           // q half (32 q)
    const int m0 = blockIdx.x * 128;
    const int q0 = blockIdx.y * 64;

    // staging constants: chunk c = i*256 + tid; row/col = c>>2, k4 = c&3
    const int rc  = tid >> 2;                                   // 0..63
    const int xk  = ((tid & 3) ^ ((tid >> 3) & 3)) * 8;         // XOR'd k-chunk
    const int stgA = (m0 + rc) * En + xk;        // A rows rc, rc+64
    const int stgB = (q0 + rc) * En + xk;        // B strips: +i*QD*En per head

    // fragment ds_read bases (f16 idx); xor nibble lane-constant
    const int xf  = (l >> 1) & 3;
    const int kx  = ((l >> 4) ^ xf) * 8;
    const int aFrag = (wm * 64 + (l & 15)) * 32 + kx;            // + m*512
    const int bFrag = 4096 + (wn * 32 + (l & 15)) * 32 + kx;     // + h*2048 + qs*512

    f32x4 acc[4][8];   // [m][f = h*2 + qsub]
    #pragma unroll
    for (int m = 0; m < 4; ++m)
        #pragma unroll
        for (int f = 0; f < 8; ++f) acc[m][f] = (f32x4){0.f, 0.f, 0.f, 0.f};

    auto stage1 = [&](int t) {
        const f16* As = (t < 16) ? Ah : ((t < 32) ? Al : Ah);
        const f16* Bs = (t < 32) ? Bht : Blt;
        const int kofs = (t & 15) * 32;
        f16* dst = lds_f + (t % 3) * 12288 + wv * 512;
        G2L(As + stgA + kofs,                dst);
        G2L(As + stgA + 64 * En + kofs,      dst + 2048);
        G2L(Bs + stgB + kofs,                dst + 4096);
        G2L(Bs + stgB + QD * En + kofs,      dst + 4096 + 2048);
        G2L(Bs + stgB + 2 * QD * En + kofs,  dst + 4096 + 4096);
        G2L(Bs + stgB + 3 * QD * En + kofs,  dst + 4096 + 6144);
    };

    // prologue: tiles 0,1 staged; wait tile0 (6 of tile1 outstanding)
    stage1(0);
    stage1(1);
    VM6;
    __builtin_amdgcn_s_barrier();

    #pragma unroll
    for (int t = 0; t < 48; ++t) {
        const f16* Lb = lds_f + (t % 3) * 12288;
        f16x8 af[4], bfr[8];
        #pragma unroll
        for (int m = 0; m < 4; ++m) af[m] = *(const f16x8*)(Lb + aFrag + m * 512);
        #pragma unroll
        for (int f = 0; f < 8; ++f)
            bfr[f] = *(const f16x8*)(Lb + bFrag + (f >> 1) * 2048 + (f & 1) * 512);
        if (t + 2 < 48) stage1(t + 2);
        __builtin_amdgcn_s_barrier();
        asm volatile("s_waitcnt lgkmcnt(0)" ::: "memory");
        __builtin_amdgcn_sched_barrier(0);
        __builtin_amdgcn_s_setprio(1);
        #pragma unroll
        for (int m = 0; m < 4; ++m) {
            #pragma unroll
            for (int f = 0; f < 8; ++f)
                acc[m][f] = __builtin_amdgcn_mfma_f32_16x16x32_f16(
                    af[m], bfr[f], acc[m][f], 0, 0, 0);
        }
        __builtin_amdgcn_s_setprio(0);
        if (t <= 45)      VM6;   // tile t+1 landed (tile t+2's 6 remain)
        else if (t == 46) VM0;   // drain: tile 47 landed
        __builtin_amdgcn_s_barrier();
    }

    // epilogue: leaky_relu + head combine + hi/lo split store
    const float w0 = wcomb[0], w1 = wcomb[1], w2 = wcomb[2], w3 = wcomb[3];
    const int rbase = m0 + wm * 64 + (l >> 4) * 4;
    #pragma unroll
    for (int m = 0; m < 4; ++m) {
        #pragma unroll
        for (int qs = 0; qs < 2; ++qs) {
            const int q = q0 + wn * 32 + qs * 16 + (l & 15);
            #pragma unroll
            for (int i = 0; i < 4; ++i) {
                float x0 = acc[m][0 + qs][i]; x0 = x0 >= 0.f ? x0 : SLOPE * x0;
                float x1 = acc[m][2 + qs][i]; x1 = x1 >= 0.f ? x1 : SLOPE * x1;
                float x2 = acc[m][4 + qs][i]; x2 = x2 >= 0.f ? x2 : SLOPE * x2;
                float x3 = acc[m][6 + qs][i]; x3 = x3 >= 0.f ? x3 : SLOPE * x3;
                const float c = w0 * x0 + w1 * x1 + w2 * x2 + w3 * x3;
                const f16 ch = (f16)c;
                const f16 cl = (f16)(c - (float)ch);
                const size_t off = (size_t)(rbase + m * 16 + i) * QD + q;
                Ch[off] = ch;
                Cl[off] = cl;
            }
        }
    }
}

// ---------------------------------------------------------------------------
// K2: out[t,b,s] = dot(combined[b,s,:], query[t,b,:]) — unchanged from R7.
//   Per batch M=1024(s) N=512(t) K=256x3. 128x128 tile, BK=32, ring-3,
//   24 K-tiles, 4 waves (2M x 2N), 16 MFMA/phase, vmcnt(4).
// ---------------------------------------------------------------------------
__global__ __launch_bounds__(256) void gemm2_kernel(
    const f16* __restrict__ Ch, const f16* __restrict__ Cl,
    const f16* __restrict__ Qh, const f16* __restrict__ Ql,
    const void* __restrict__ maskp, const float* __restrict__ wcomb,
    const int* __restrict__ flag,
    float* __restrict__ out)
{
    __shared__ f16 lds2[24576];   // 3 slots x (A 4096 + B 4096) f16

    const int tid = threadIdx.x;
    const int l  = tid & 63;
    const int wv = tid >> 6;
    const int wm = wv >> 1;          // s half
    const int wn = wv & 1;           // t half
    const int b  = blockIdx.z;
    const int s0 = blockIdx.x * 128;
    const int t0 = blockIdx.y * 128;

    const int rowc = tid >> 2;
    const int xk   = ((tid & 3) ^ ((rowc >> 1) & 3)) * 8;
    const int stgA = (b * Sn + s0 + rowc) * QD + xk;   // +64*QD instr2
    const int stgB = (b * Tn + t0 + rowc) * QD + xk;   // +64*QD instr2

    const int xf  = ((l >> 1) & 3);
    const int aFrag = (wm * 64 + (l & 15)) * 32 + (((l >> 4) ^ xf) * 8);
    const int bFrag = 4096 + (wn * 64 + (l & 15)) * 32 + (((l >> 4) ^ xf) * 8);

    f32x4 acc[4][4];
    #pragma unroll
    for (int m = 0; m < 4; ++m)
        #pragma unroll
        for (int n = 0; n < 4; ++n) acc[m][n] = (f32x4){0.f, 0.f, 0.f, 0.f};

    auto stage1 = [&](int t) {
        const f16* As = (t < 8) ? Ch : ((t < 16) ? Cl : Ch);
        const f16* Bs = (t < 16) ? Qh : Ql;
        const int kofs = (t & 7) * 32;
        f16* dst = lds2 + (t % 3) * 8192 + wv * 512;
        G2L(As + stgA + kofs,           dst);
        G2L(As + stgA + 64 * QD + kofs, dst + 2048);
        G2L(Bs + stgB + kofs,           dst + 4096);
        G2L(Bs + stgB + 64 * QD + kofs, dst + 4096 + 2048);
    };

    stage1(0);
    stage1(1);
    VM4;
    __builtin_amdgcn_s_barrier();

    #pragma unroll
    for (int kt = 0; kt < 24; ++kt) {
        const f16* Lb = lds2 + (kt % 3) * 8192;
        f16x8 af[4], bfr[4];
        #pragma unroll
        for (int m = 0; m < 4; ++m) af[m] = *(const f16x8*)(Lb + aFrag + m * 512);
        #pragma unroll
        for (int n = 0; n < 4; ++n) bfr[n] = *(const f16x8*)(Lb + bFrag + n * 512);
        if (kt + 2 < 24) stage1(kt + 2);
        __builtin_amdgcn_s_barrier();
        asm volatile("s_waitcnt lgkmcnt(0)" ::: "memory");
        __builtin_amdgcn_sched_barrier(0);
        __builtin_amdgcn_s_setprio(1);
        #pragma unroll
        for (int m = 0; m < 4; ++m) {
            #pragma unroll
            for (int n = 0; n < 4; ++n)
                acc[m][n] = __builtin_amdgcn_mfma_f32_16x16x32_f16(
                    af[m], bfr[n], acc[m][n], 0, 0, 0);
        }
        __builtin_amdgcn_s_setprio(0);
        if (kt <= 21)      VM4;
        else if (kt == 22) VM0;
        __builtin_amdgcn_s_barrier();
    }

    // epilogue: mask override + coalesced float4 stores along s
    const float sumw = wcomb[0] + wcomb[1] + wcomb[2] + wcomb[3];
    const float maskval = NEG_INF * sumw;
    const bool is_int = (flag[0] != 0);
    const int rbase = s0 + wm * 64 + (l >> 4) * 4;

    bool msk[4][4];
    #pragma unroll
    for (int m = 0; m < 4; ++m)
        #pragma unroll
        for (int i = 0; i < 4; ++i) {
            const int idx = b * Sn + rbase + m * 16 + i;
            int mm;
            if (is_int) mm = ((const int*)maskp)[idx];
            else        mm = (int)((const unsigned char*)maskp)[idx];
            msk[m][i] = (mm != 0);
        }

    #pragma unroll
    for (int m = 0; m < 4; ++m)
        #pragma unroll
        for (int n = 0; n < 4; ++n) {
            const int t = t0 + wn * 64 + n * 16 + (l & 15);
            float vals[4];
            #pragma unroll
            for (int i = 0; i < 4; ++i)
                vals[i] = msk[m][i] ? maskval : acc[m][n][i];
            *(float4*)(out + ((size_t)t * Bn + b) * Sn + rbase + m * 16)
                = make_float4(vals[0], vals[1], vals[2], vals[3]);
        }
}

// ---------------------------------------------------------------------------
// K3: in-place softmax over last dim (S=1024). One block per (t,b) row.
// ---------------------------------------------------------------------------
__global__ __launch_bounds__(256) void softmax_kernel(float* __restrict__ out) {
    const size_t row = blockIdx.x;
    float* p = out + row * (size_t)Sn;
    const int tid = threadIdx.x;
    const int lane = tid & 63, wave = tid >> 6;

    float4 v = ((const float4*)p)[tid];

    float m = fmaxf(fmaxf(v.x, v.y), fmaxf(v.z, v.w));
    #pragma unroll
    for (int off = 32; off; off >>= 1) m = fmaxf(m, __shfl_down(m, off));
    __shared__ float smax[4];
    __shared__ float sm_all;
    if (lane == 0) smax[wave] = m;
    __syncthreads();
    if (tid == 0) sm_all = fmaxf(fmaxf(smax[0], smax[1]), fmaxf(smax[2], smax[3]));
    __syncthreads();
    m = sm_all;

    float e0 = __expf(v.x - m), e1 = __expf(v.y - m);
    float e2 = __expf(v.z - m), e3 = __expf(v.w - m);
    float s = e0 + e1 + e2 + e3;
    #pragma unroll
    for (int off = 32; off; off >>= 1) s += __shfl_down(s, off);
    __shared__ float ssum[4];
    __shared__ float ss_all;
    if (lane == 0) ssum[wave] = s;
    __syncthreads();
    if (tid == 0) ss_all = ssum[0] + ssum[1] + ssum[2] + ssum[3];
    __syncthreads();
    const float inv = 1.0f / ss_all;

    ((float4*)p)[tid] = make_float4(e0 * inv, e1 * inv, e2 * inv, e3 * inv);
}

// ---------------------------------------------------------------------------
extern "C" void kernel_launch(void* const* d_in, const int* in_sizes, int n_in,
                              void* d_out, int out_size, void* d_ws, size_t ws_size,
                              hipStream_t stream) {
    const float* src   = (const float*)d_in[0];  // (16,1024,512)
    const void*  maskp = d_in[1];                // (16,1024) bool/int32
    const float* query = (const float*)d_in[2];  // (512,16,256)
    const float* Wsrc  = (const float*)d_in[3];  // (512,1024)
    const float* wcomb = (const float*)d_in[4];  // (4,)
    float* out = (float*)d_out;                  // (512,16,1024)

    // workspace layout (total 50 MB + 256 B; Qh/Ql alias Ah/Al after gemm1)
    constexpr size_t MB = 1024 * 1024;
    char* ws = (char*)d_ws;
    int* flag = (int*)ws;
    f16* Ah  = (f16*)(ws + 256);
    f16* Al  = (f16*)(ws + 256 + 16 * MB);
    f16* Bht = (f16*)(ws + 256 + 32 * MB);
    f16* Blt = (f16*)(ws + 256 + 33 * MB);
    f16* Ch  = (f16*)(ws + 256 + 34 * MB);
    f16* Cl  = (f16*)(ws + 256 + 42 * MB);
    f16* Qh  = (f16*)(ws + 256);            // aliases Ah (free after gemm1)
    f16* Ql  = (f16*)(ws + 256 + 4 * MB);   // aliases Ah region

    detect_mask_kernel<<<1, 256, 0, stream>>>((const unsigned char*)maskp, flag);

    conv_a_kernel<<<(Mn * En) / (256 * 4), 256, 0, stream>>>(src, Ah, Al);
    {
        dim3 grid((Hn * QD) / 64, En / 64);  // (16, 8)
        conv_b_kernel<<<grid, 256, 0, stream>>>(Wsrc, Bht, Blt);
    }
    {
        dim3 grid(Mn / 128, QD / 64);        // (128, 4) = 512 blocks, 2/CU
        gemm1_kernel<<<grid, 256, 0, stream>>>(Ah, Al, Bht, Blt, wcomb, Ch, Cl);
    }
    conv_q_kernel<<<(Tn * Bn) / 4, 256, 0, stream>>>(query, Qh, Ql);
    {
        dim3 grid(Sn / 128, Tn / 128, Bn);   // (8, 4, 16) = 512 blocks
        gemm2_kernel<<<grid, 256, 0, stream>>>(Ch, Cl, Qh, Ql, maskp, wcomb, flag, out);
    }
    softmax_kernel<<<Tn * Bn, 256, 0, stream>>>(out);
}